// Round 7
// baseline (2612.757 us; speedup 1.0000x reference)
//
#include <hip/hip_runtime.h>
#include <hip/hip_bf16.h>
#include <cstddef>

// Problem constants
constexpr int B = 128;
constexpr int T = 500;
constexpr int C = 128;     // n_maps
constexpr int CIN = 80;    // n_mels
constexpr int NL = 35;     // labels
constexpr size_t NBCT = (size_t)B * C * T;  // 8,192,000 floats
constexpr int WPAD = 132;                   // LDS i-stride (2-way alias = free)
constexpr int I0 = 96;                      // conv0 padded input channels
constexpr int IPAD0 = 104;                  // conv0 LDS i-stride
constexpr int NT = 64;                      // conv t-tile
constexpr int NSLOT = 49;                   // stats slots: 16*(t1,t3,t2) + conv0

typedef __attribute__((ext_vector_type(8))) _Float16 half8;  // 8 fp16 = 4 VGPR
typedef __attribute__((ext_vector_type(4))) _Float16 half4;
typedef __attribute__((ext_vector_type(4))) float f32x4;
typedef __attribute__((ext_vector_type(16))) float f32x16;  // 32x32 acc

// Static device scratch. Activations in [b][t][c] layout.
__device__ float g_z[NBCT];          // RK4 state (fp32)
__device__ float g_acc[NBCT];        // RK4 k-accumulator (fp32)
__device__ _Float16 g_zi16[NBCT];    // conv input snapshot (fp16)
__device__ _Float16 g_t1[NBCT];      // conv1 out (fp16, pre-BN)
__device__ _Float16 g_t2[NBCT];      // conv2 out (fp16, pre-BN)
__device__ _Float16 g_t3[NBCT];      // conv3 out (fp16, pre-BN)
__device__ float g_S[NSLOT * C], g_Q[NSLOT * C];  // global stat accumulators
__device__ float g_featp[B * 4 * C];              // head partial sums
// conv0 weights, layout [kw][o][i] (i-stride I0), fp16
__device__ _Float16 g_w0f[3 * C * I0];
// main conv weights, MFMA-native layout [kw][kseg=i>>3][o][j=i&7], fp16
__device__ _Float16 g_w1f[9 * C * C];
__device__ _Float16 g_w2f[9 * C * C];
__device__ _Float16 g_w3f[1 * C * C];

__device__ inline half8 h8zero() {
  half8 v;
#pragma unroll
  for (int j = 0; j < 8; j++) v[j] = (_Float16)0.f;
  return v;
}
__device__ inline f32x16 f16zero() {
  f32x16 v;
#pragma unroll
  for (int j = 0; j < 16; j++) v[j] = 0.f;
  return v;
}

// ---------------------------------------------------------------------------
// Zero the stat accumulators (once per launch, up front).
// ---------------------------------------------------------------------------
__global__ __launch_bounds__(256) void zero_stats(float* __restrict__ S,
                                                  float* __restrict__ Q) {
  int i = blockIdx.x * 256 + threadIdx.x;
  if (i < NSLOT * C) {
    S[i] = 0.f;
    Q[i] = 0.f;
  }
}

// ---------------------------------------------------------------------------
// Weight prep: w [O][I][KW] fp32 -> fp16, layout [kw][i>>3][o][i&7]
// ---------------------------------------------------------------------------
template <int KW>
__global__ __launch_bounds__(256) void prep_weights_f16(
    const float* __restrict__ w, _Float16* __restrict__ wf) {
  int idx = blockIdx.x * 256 + threadIdx.x;
  if (idx >= C * C * KW) return;
  int kw = idx % KW;
  int i = (idx / KW) % C;
  int o = idx / (KW * C);
  size_t dst = (((size_t)kw * 16 + (i >> 3)) * C + o) * 8 + (i & 7);
  wf[dst] = (_Float16)w[idx];
}

// conv0 weights: w0 [O=128][I=80][3] -> [3][O][I0=96] fp16 (zero-padded i>=80)
__global__ __launch_bounds__(256) void prep_w0_f16(
    const float* __restrict__ w, _Float16* __restrict__ wf) {
  int idx = blockIdx.x * 256 + threadIdx.x;
  if (idx >= 3 * C * I0) return;
  int i = idx % I0;
  int o = (idx / I0) % C;
  int kw = idx / (I0 * C);
  float v = 0.f;
  if (i < CIN) v = w[((size_t)o * CIN + i) * 3 + kw];
  wf[((size_t)kw * C + o) * I0 + i] = (_Float16)v;
}

// ---------------------------------------------------------------------------
// 16x16 epilogue (conv0 only): store D tiles (fp32) + per-channel stats.
// D layout (16x16x32): col(t)=lane&15, row(o)=quad*4+reg.
// ---------------------------------------------------------------------------
template <int NG, int NTG>
__device__ inline void store_and_stats_f(f32x4 (&dacc)[NG][NTG],
                                         float* __restrict__ outb,
                                         float* __restrict__ ssum,
                                         float* __restrict__ ssq, int tbase,
                                         int og0, int quad, int m15) {
#pragma unroll
  for (int g = 0; g < NG; g++) {
    float rs[4] = {0.f, 0.f, 0.f, 0.f}, rq[4] = {0.f, 0.f, 0.f, 0.f};
#pragma unroll
    for (int tg = 0; tg < NTG; tg++) {
      int t = tbase + tg * 16 + m15;
      bool valid = t < T;
      f32x4 d = dacc[g][tg];
      if (valid)
        *(f32x4*)(outb + (size_t)t * C + (og0 + g) * 16 + quad * 4) = d;
#pragma unroll
      for (int r = 0; r < 4; r++) {
        float v = valid ? d[r] : 0.f;
        rs[r] += v;
        rq[r] += v * v;
      }
    }
#pragma unroll
    for (int sh = 1; sh < 16; sh <<= 1) {
#pragma unroll
      for (int r = 0; r < 4; r++) {
        rs[r] += __shfl_xor(rs[r], sh);
        rq[r] += __shfl_xor(rq[r], sh);
      }
    }
    if (m15 == 0) {
      int o = (og0 + g) * 16 + quad * 4;
#pragma unroll
      for (int r = 0; r < 4; r++) {
        atomicAdd(&ssum[o + r], rs[r]);
        atomicAdd(&ssq[o + r], rq[r]);
      }
    }
  }
}

// ---------------------------------------------------------------------------
// 32x32 epilogue: store fp16 + per-channel stats. D layout (32x32x16):
// col(t)=lane&31, row(o)=(reg&3)+8*(reg>>2)+4*(lane>>5), reg in [0,16).
// So o = og*32 + 8q + 4h + rr (q=reg>>2, rr=reg&3, h=lane>>5) — each reg
// quad is 4 consecutive channels -> half4 stores.
// ---------------------------------------------------------------------------
__device__ inline void store_stats32(f32x16 (&d)[2], _Float16* __restrict__ outb,
                                     float* __restrict__ ssum,
                                     float* __restrict__ ssq, int t0, int og,
                                     int l31, int h) {
#pragma unroll
  for (int q = 0; q < 4; q++) {
    float rs[4] = {0.f, 0.f, 0.f, 0.f}, rq[4] = {0.f, 0.f, 0.f, 0.f};
#pragma unroll
    for (int tg = 0; tg < 2; tg++) {
      int t = t0 + tg * 32 + l31;
      bool valid = t < T;
      half4 h4;
#pragma unroll
      for (int rr = 0; rr < 4; rr++) {
        float v = d[tg][q * 4 + rr];
        h4[rr] = (_Float16)v;
        float vv = valid ? v : 0.f;
        rs[rr] += vv;
        rq[rr] += vv * vv;
      }
      if (valid)
        *(half4*)(outb + (size_t)t * C + og * 32 + 8 * q + 4 * h) = h4;
    }
#pragma unroll
    for (int sh = 1; sh < 32; sh <<= 1) {
#pragma unroll
      for (int rr = 0; rr < 4; rr++) {
        rs[rr] += __shfl_xor(rs[rr], sh);
        rq[rr] += __shfl_xor(rq[rr], sh);
      }
    }
    if (l31 == 0) {
      int o = og * 32 + 8 * q + 4 * h;
#pragma unroll
      for (int rr = 0; rr < 4; rr++) {
        atomicAdd(&ssum[o + rr], rs[rr]);
        atomicAdd(&ssq[o + rr], rq[rr]);
      }
    }
  }
}

// ---------------------------------------------------------------------------
// Fused conv1 (KW=9, PAD=4) + conv3 (KW=1) with 32x32x16 MFMA.
// 256 thr / 4 waves; wave wv owns o-tile og=wv (32 channels), both t-tiles
// (NTG=2 x 32). Per round (kw, ic16): 1 global A-load + 2 LDS B-reads ->
// 2 MFMA. vs 16x16 path: A-bytes and VMEM/LDS/MFMA inst counts halved at
// equal FLOP. A-frag: lane l holds W[o=og*32+(l&31)][k=ic16*16+(l>>5)*8+j]
// (prep layout [kw][i>>3][o][i&7] => half8 idx (kw*16+ic16*2+h)*C+og*32+l31).
// conv3 computes first and retires its accumulator (32 VGPR) before conv1.
// ---------------------------------------------------------------------------
__global__ __launch_bounds__(256, 4) void conv13(
    const _Float16* __restrict__ in, const _Float16* __restrict__ w9,
    const _Float16* __restrict__ w1, _Float16* __restrict__ out1,
    _Float16* __restrict__ out3, float* __restrict__ gS1,
    float* __restrict__ gQ1, float* __restrict__ gS3,
    float* __restrict__ gQ3) {
  constexpr int PAD = 4;
  constexpr int ROWS = NT + 8;  // 72
  __shared__ __align__(16) _Float16 sh[ROWS * WPAD];
  __shared__ float ssum1[C], ssq1[C], ssum3[C], ssq3[C];

  const int tid = threadIdx.x;
  const int tile = blockIdx.x;
  const int b = blockIdx.y;
  const int t0 = tile * NT;

  if (tid < 128) {
    ssum1[tid] = 0.f; ssq1[tid] = 0.f;
    ssum3[tid] = 0.f; ssq3[tid] = 0.f;
  }

  // Stage fp16 rows [t0-PAD, t0-PAD+ROWS) — pure copy, 16B loads.
  const _Float16* __restrict__ inb = in + (size_t)b * T * C;
  for (int e = tid; e < ROWS * 16; e += 256) {
    int r = e >> 4;
    int c8 = e & 15;
    int t = t0 - PAD + r;
    half8 v = h8zero();
    if (t >= 0 && t < T) v = *(const half8*)(inb + (size_t)t * C + c8 * 8);
    *(half8*)&sh[r * WPAD + c8 * 8] = v;
  }
  __syncthreads();

  const int wv = tid >> 6;
  const int lane = tid & 63;
  const int l31 = lane & 31;
  const int h = lane >> 5;
  const int og = wv;

  const half8* __restrict__ A9 = (const half8*)w9;
  const half8* __restrict__ A1 = (const half8*)w1;
  const int aoff = og * 32 + l31;

  // --- conv3 (KW=1): 8 rounds, retire accumulator early ---
  {
    f32x16 d3[2] = {f16zero(), f16zero()};
#pragma unroll
    for (int ic16 = 0; ic16 < 8; ic16++) {
      half8 a = A1[(ic16 * 2 + h) * C + aoff];
      const int kof = ic16 * 16 + h * 8;
      half8 b0 = *(const half8*)(sh + (l31 + PAD) * WPAD + kof);
      half8 b1 = *(const half8*)(sh + (32 + l31 + PAD) * WPAD + kof);
      d3[0] = __builtin_amdgcn_mfma_f32_32x32x16_f16(a, b0, d3[0], 0, 0, 0);
      d3[1] = __builtin_amdgcn_mfma_f32_32x32x16_f16(a, b1, d3[1], 0, 0, 0);
    }
    _Float16* __restrict__ o3b = out3 + (size_t)b * T * C;
    store_stats32(d3, o3b, ssum3, ssq3, t0, og, l31, h);
  }

  // --- conv1 (KW=9): 72 rounds ---
  f32x16 d1[2] = {f16zero(), f16zero()};
  for (int kw = 0; kw < 9; kw++) {
#pragma unroll
    for (int ic16 = 0; ic16 < 8; ic16++) {
      half8 a = A9[(kw * 16 + ic16 * 2 + h) * C + aoff];
      const int kof = ic16 * 16 + h * 8;
      half8 b0 = *(const half8*)(sh + (l31 + kw) * WPAD + kof);
      half8 b1 = *(const half8*)(sh + (32 + l31 + kw) * WPAD + kof);
      d1[0] = __builtin_amdgcn_mfma_f32_32x32x16_f16(a, b0, d1[0], 0, 0, 0);
      d1[1] = __builtin_amdgcn_mfma_f32_32x32x16_f16(a, b1, d1[1], 0, 0, 0);
    }
  }

  _Float16* __restrict__ o1b = out1 + (size_t)b * T * C;
  store_stats32(d1, o1b, ssum1, ssq1, t0, og, l31, h);
  __syncthreads();
  if (tid < 128) {
    atomicAdd(&gS1[tid], ssum1[tid]);
    atomicAdd(&gQ1[tid], ssq1[tid]);
    atomicAdd(&gS3[tid], ssum3[tid]);
    atomicAdd(&gQ3[tid], ssq3[tid]);
  }
}

// ---------------------------------------------------------------------------
// conv2 (KW=9, PAD=4): BN+relu on staging from inline stats; 32x32x16 MFMA.
// ---------------------------------------------------------------------------
__global__ __launch_bounds__(256, 4) void conv2_bn(
    const _Float16* __restrict__ in, const _Float16* __restrict__ wf,
    const float* __restrict__ bnS, const float* __restrict__ bnQ,
    _Float16* __restrict__ out, float* __restrict__ gS,
    float* __restrict__ gQ) {
  constexpr int PAD = 4;
  constexpr int ROWS = NT + 8;  // 72
  __shared__ __align__(16) _Float16 sh[ROWS * WPAD];
  __shared__ float ssum[C], ssq[C];
  __shared__ float sbm[C], sbr[C];

  const int tid = threadIdx.x;
  const int tile = blockIdx.x;
  const int b = blockIdx.y;
  const int t0 = tile * NT;

  if (tid < 128) {
    const float invn = 1.f / 64000.f;
    float m = bnS[tid] * invn;
    sbm[tid] = m;
    sbr[tid] = rsqrtf(bnQ[tid] * invn - m * m + 1e-5f);
    ssum[tid] = 0.f;
    ssq[tid] = 0.f;
  }
  __syncthreads();  // BN params ready before staging uses them

  const _Float16* __restrict__ inb = in + (size_t)b * T * C;
  for (int e = tid; e < ROWS * 16; e += 256) {
    int r = e >> 4;
    int c8 = e & 15;
    int t = t0 - PAD + r;
    half8 v = h8zero();
    if (t >= 0 && t < T) {
      half8 u = *(const half8*)(inb + (size_t)t * C + c8 * 8);
      int c = c8 * 8;
#pragma unroll
      for (int j = 0; j < 8; j++) {
        float f = (float)u[j];
        f = fmaxf((f - sbm[c + j]) * sbr[c + j], 0.f);
        v[j] = (_Float16)f;
      }
    }
    *(half8*)&sh[r * WPAD + c8 * 8] = v;
  }
  __syncthreads();

  const int wv = tid >> 6;
  const int lane = tid & 63;
  const int l31 = lane & 31;
  const int h = lane >> 5;
  const int og = wv;

  const half8* __restrict__ Af = (const half8*)wf;
  const int aoff = og * 32 + l31;

  f32x16 dacc[2] = {f16zero(), f16zero()};
  for (int kw = 0; kw < 9; kw++) {
#pragma unroll
    for (int ic16 = 0; ic16 < 8; ic16++) {
      half8 a = Af[(kw * 16 + ic16 * 2 + h) * C + aoff];
      const int kof = ic16 * 16 + h * 8;
      half8 b0 = *(const half8*)(sh + (l31 + kw) * WPAD + kof);
      half8 b1 = *(const half8*)(sh + (32 + l31 + kw) * WPAD + kof);
      dacc[0] = __builtin_amdgcn_mfma_f32_32x32x16_f16(a, b0, dacc[0], 0, 0, 0);
      dacc[1] = __builtin_amdgcn_mfma_f32_32x32x16_f16(a, b1, dacc[1], 0, 0, 0);
    }
  }

  _Float16* __restrict__ outb = out + (size_t)b * T * C;
  store_stats32(dacc, outb, ssum, ssq, t0, og, l31, h);
  __syncthreads();
  if (tid < 128) {
    atomicAdd(&gS[tid], ssum[tid]);
    atomicAdd(&gQ[tid], ssq[tid]);
  }
}

// ---------------------------------------------------------------------------
// conv0: single fp16 16x16x32 MFMA. in x[B][80][T] (t fastest), K=96(pad) x 3.
// Output z fp32 (state). 256 threads, one dispatch — unchanged.
// ---------------------------------------------------------------------------
__global__ __launch_bounds__(256) void conv0_mfma(
    const float* __restrict__ in, const _Float16* __restrict__ wf,
    float* __restrict__ out, float* __restrict__ gS, float* __restrict__ gQ) {
  constexpr int KW = 3, PAD = 1;
  constexpr int ROWS = NT + KW - 1;  // 66
  __shared__ __align__(16) _Float16 sh[ROWS * IPAD0];
  __shared__ float ssum[C], ssq[C];

  const int tid = threadIdx.x;
  const int tile = blockIdx.x;
  const int b = blockIdx.y;
  const int t0 = tile * NT;

  if (tid < 128) { ssum[tid] = 0.f; ssq[tid] = 0.f; }
  __syncthreads();

  const float* __restrict__ inb = in + (size_t)b * CIN * T;
  for (int e = tid; e < I0 * ROWS; e += 256) {
    int i = e / ROWS;
    int r = e % ROWS;
    int t = t0 - PAD + r;
    float v = 0.f;
    if (i < CIN && t >= 0 && t < T) v = inb[(size_t)i * T + t];
    sh[r * IPAD0 + i] = (_Float16)v;
  }
  __syncthreads();

  const int wv = tid >> 6;
  const int lane = tid & 63;
  const int quad = lane >> 4;
  const int m15 = lane & 15;
  const int og0 = wv * 2;

  f32x4 dacc[2][4];
#pragma unroll
  for (int g = 0; g < 2; g++)
#pragma unroll
    for (int tg = 0; tg < 4; tg++) dacc[g][tg] = f32x4{0.f, 0.f, 0.f, 0.f};

  for (int kw = 0; kw < KW; kw++) {
    const _Float16* __restrict__ wk = wf + (size_t)kw * C * I0;
#pragma unroll
    for (int ic = 0; ic < 3; ic++) {
      const int kof = ic * 32 + quad * 8;
      half8 af[2];
#pragma unroll
      for (int g = 0; g < 2; g++) {
        size_t off = (size_t)((og0 + g) * 16 + m15) * I0 + kof;
        af[g] = *(const half8*)(wk + off);
      }
      half8 bf[4];
#pragma unroll
      for (int tg = 0; tg < 4; tg++) {
        int off = (tg * 16 + m15 + kw) * IPAD0 + kof;
        bf[tg] = *(const half8*)(sh + off);
      }
#pragma unroll
      for (int g = 0; g < 2; g++)
#pragma unroll
        for (int tg = 0; tg < 4; tg++)
          dacc[g][tg] = __builtin_amdgcn_mfma_f32_16x16x32_f16(
              af[g], bf[tg], dacc[g][tg], 0, 0, 0);
    }
  }

  float* __restrict__ outb = out + (size_t)b * T * C;
  store_and_stats_f<2, 4>(dacc, outb, ssum, ssq, t0, og0, quad, m15);
  __syncthreads();
  if (tid < 128) {
    atomicAdd(&gS[tid], ssum[tid]);
    atomicAdd(&gQ[tid], ssq[tid]);
  }
}

// ---------------------------------------------------------------------------
// z = relu((z - m[c]) * r[c]) in place (fp32) + fp16 snapshot for conv13.
// ---------------------------------------------------------------------------
__global__ __launch_bounds__(256) void apply_bn_relu(
    float* __restrict__ x, const float* __restrict__ S,
    const float* __restrict__ Q, _Float16* __restrict__ zh) {
  __shared__ float sm[C], sr[C];
  if (threadIdx.x < 128) {
    const float invn = 1.f / 64000.f;
    float m = S[threadIdx.x] * invn;
    sm[threadIdx.x] = m;
    sr[threadIdx.x] = rsqrtf(Q[threadIdx.x] * invn - m * m + 1e-5f);
  }
  __syncthreads();
  const size_t total4 = NBCT / 4;
  size_t stride = (size_t)gridDim.x * 256;
  for (size_t i4 = (size_t)blockIdx.x * 256 + threadIdx.x; i4 < total4;
       i4 += stride) {
    int c = (int)((i4 & 31) * 4);
    float4 v = ((float4*)x)[i4];
    v.x = fmaxf((v.x - sm[c]) * sr[c], 0.f);
    v.y = fmaxf((v.y - sm[c + 1]) * sr[c + 1], 0.f);
    v.z = fmaxf((v.z - sm[c + 2]) * sr[c + 2], 0.f);
    v.w = fmaxf((v.w - sm[c + 3]) * sr[c + 3], 0.f);
    ((float4*)x)[i4] = v;
    half4 h;
    h[0] = (_Float16)v.x;
    h[1] = (_Float16)v.y;
    h[2] = (_Float16)v.z;
    h[3] = (_Float16)v.w;
    *(half4*)(zh + i4 * 4) = h;
  }
}

// ---------------------------------------------------------------------------
// combine: k = relu(bn2(t2) + relu(bn3(t3))); RK4 update.
// t2/t3 fp16; z/acc fp32; zi16 (fp16 next-conv input) always written;
// z (fp32 state) written only on fin.
// ---------------------------------------------------------------------------
__global__ __launch_bounds__(256) void combine_kernel(
    const _Float16* __restrict__ t2, const _Float16* __restrict__ t3,
    const float* __restrict__ S2, const float* __restrict__ Q2,
    const float* __restrict__ S3, const float* __restrict__ Q3,
    float* __restrict__ z, float* __restrict__ acc,
    _Float16* __restrict__ zi16, float wacc, float anext, int init, int fin) {
  __shared__ float sm2[C], sr2[C], sm3[C], sr3[C];
  if (threadIdx.x < 128) {
    const float invn = 1.f / 64000.f;
    float m2v = S2[threadIdx.x] * invn;
    sm2[threadIdx.x] = m2v;
    sr2[threadIdx.x] = rsqrtf(Q2[threadIdx.x] * invn - m2v * m2v + 1e-5f);
    float m3v = S3[threadIdx.x] * invn;
    sm3[threadIdx.x] = m3v;
    sr3[threadIdx.x] = rsqrtf(Q3[threadIdx.x] * invn - m3v * m3v + 1e-5f);
  }
  __syncthreads();
  const size_t total4 = NBCT / 4;
  size_t stride = (size_t)gridDim.x * 256;
  for (size_t i4 = (size_t)blockIdx.x * 256 + threadIdx.x; i4 < total4;
       i4 += stride) {
    int c = (int)((i4 & 31) * 4);
    size_t off = i4 * 4;
    half4 h2 = *(const half4*)(t2 + off);
    half4 h3 = *(const half4*)(t3 + off);
    float4 vz = *(const float4*)(z + off);
    float k[4];
#pragma unroll
    for (int j = 0; j < 4; j++) {
      float f2 = (float)h2[j];
      float f3 = (float)h3[j];
      k[j] = fmaxf((f2 - sm2[c + j]) * sr2[c + j] +
                       fmaxf((f3 - sm3[c + j]) * sr3[c + j], 0.f),
                   0.f);
    }
    float va[4];
    if (init) {
#pragma unroll
      for (int j = 0; j < 4; j++) va[j] = wacc * k[j];
    } else {
      float4 a = *(const float4*)(acc + off);
      va[0] = a.x + wacc * k[0];
      va[1] = a.y + wacc * k[1];
      va[2] = a.z + wacc * k[2];
      va[3] = a.w + wacc * k[3];
    }
    float vzf[4] = {vz.x, vz.y, vz.z, vz.w};
    float vo[4];
    if (fin) {
#pragma unroll
      for (int j = 0; j < 4; j++) vo[j] = vzf[j] + anext * va[j];
      float4 w4 = make_float4(vo[0], vo[1], vo[2], vo[3]);
      *(float4*)(z + off) = w4;
    } else {
      float4 a4 = make_float4(va[0], va[1], va[2], va[3]);
      *(float4*)(acc + off) = a4;
#pragma unroll
      for (int j = 0; j < 4; j++) vo[j] = vzf[j] + anext * k[j];
    }
    half4 ho;
#pragma unroll
    for (int j = 0; j < 4; j++) ho[j] = (_Float16)vo[j];
    *(half4*)(zi16 + off) = ho;
  }
}

// ---------------------------------------------------------------------------
// head, phase 1: partial t-sums. grid (B, 4), each block sums 125 t's.
// ---------------------------------------------------------------------------
__global__ __launch_bounds__(256) void feat_part(
    const float* __restrict__ z, float* __restrict__ fp) {
  const int b = blockIdx.x;
  const int s = blockIdx.y;
  const int c = threadIdx.x & 127;
  const int h = threadIdx.x >> 7;
  const float* zb = z + (size_t)b * T * C;
  float sum = 0.f;
  for (int t = s * 125 + h; t < (s + 1) * 125; t += 2)
    sum += zb[(size_t)t * C + c];
  __shared__ float sf[2][C];
  sf[h][c] = sum;
  __syncthreads();
  if (threadIdx.x < 128)
    fp[((size_t)b * 4 + s) * C + threadIdx.x] =
        sf[0][threadIdx.x] + sf[1][threadIdx.x];
}

// head, phase 2: feat = sum(partials)/500; out = feat @ ow^T + ob.
__global__ __launch_bounds__(256) void head2(
    const float* __restrict__ fp, const float* __restrict__ ow,
    const float* __restrict__ ob, float* __restrict__ out) {
  const int b = blockIdx.x;
  __shared__ float feat[C];
  if (threadIdx.x < 128) {
    float s = 0.f;
#pragma unroll
    for (int p = 0; p < 4; p++) s += fp[((size_t)b * 4 + p) * C + threadIdx.x];
    feat[threadIdx.x] = s * (1.f / 500.f);
  }
  __syncthreads();
  if (threadIdx.x < NL) {
    int l = threadIdx.x;
    float o = ob[l];
    for (int j = 0; j < C; j++) o = fmaf(feat[j], ow[l * C + j], o);
    out[b * NL + l] = o;
  }
}

// ---------------------------------------------------------------------------
extern "C" void kernel_launch(void* const* d_in, const int* in_sizes, int n_in,
                              void* d_out, int out_size, void* d_ws,
                              size_t ws_size, hipStream_t stream) {
  const float* x  = (const float*)d_in[0];
  const float* w0 = (const float*)d_in[1];
  const float* w1 = (const float*)d_in[2];
  const float* w2 = (const float*)d_in[3];
  const float* w3 = (const float*)d_in[4];
  const float* ow = (const float*)d_in[5];
  const float* ob = (const float*)d_in[6];
  float* out = (float*)d_out;

  static float *z, *acc, *Sg, *Qg, *featp;
  static _Float16 *zi16, *t1, *t2, *t3;
  static _Float16 *w0f, *w1f, *w2f, *w3f;
  static bool inited = false;
  if (!inited) {
    void* p;
#define GET(sym, var) hipGetSymbolAddress(&p, HIP_SYMBOL(sym)); var = (decltype(var))p;
    GET(g_z, z) GET(g_acc, acc) GET(g_zi16, zi16)
    GET(g_t1, t1) GET(g_t2, t2) GET(g_t3, t3)
    GET(g_S, Sg) GET(g_Q, Qg) GET(g_featp, featp)
    GET(g_w0f, w0f) GET(g_w1f, w1f) GET(g_w2f, w2f) GET(g_w3f, w3f)
#undef GET
    inited = true;
  }

  // Zero stat slots + weight prep (cheap, every launch)
  zero_stats<<<(NSLOT * C + 255) / 256, 256, 0, stream>>>(Sg, Qg);
  prep_w0_f16<<<(3 * C * I0 + 255) / 256, 256, 0, stream>>>(w0, w0f);
  prep_weights_f16<9><<<(C * C * 9 + 255) / 256, 256, 0, stream>>>(w1, w1f);
  prep_weights_f16<9><<<(C * C * 9 + 255) / 256, 256, 0, stream>>>(w2, w2f);
  prep_weights_f16<1><<<(C * C * 1 + 255) / 256, 256, 0, stream>>>(w3, w3f);

  const dim3 convGrid(8, B);   // NT=64 -> 1024 blocks of 256 thr = 4/CU
  const int ewGrid = 1024;
  const float dt = 0.25f;

  // conv0 -> bn -> relu (into z fp32 + zi16 fp16). Stats slot 48.
  float* S0 = Sg + 48 * C;
  float* Q0 = Qg + 48 * C;
  conv0_mfma<<<dim3(8, B), 256, 0, stream>>>(x, w0f, z, S0, Q0);
  apply_bn_relu<<<ewGrid, 256, 0, stream>>>(z, S0, Q0, zi16);

  const float waccs[4] = {1.f, 2.f, 2.f, 1.f};
  const float anexts[4] = {0.5f * dt, 0.5f * dt, dt, dt / 6.f};

  for (int step = 0; step < 4; step++) {
    for (int s = 0; s < 4; s++) {
      int base = ((step * 4 + s) * 3) * C;   // slots: t1, t3, t2
      float* S1 = Sg + base;       float* Q1 = Qg + base;
      float* S3 = Sg + base + C;   float* Q3 = Qg + base + C;
      float* S2 = Sg + base + 2*C; float* Q2 = Qg + base + 2*C;
      conv13<<<convGrid, 256, 0, stream>>>(
          zi16, w1f, w3f, t1, t3, S1, Q1, S3, Q3);
      conv2_bn<<<convGrid, 256, 0, stream>>>(
          t1, w2f, S1, Q1, t2, S2, Q2);
      combine_kernel<<<ewGrid, 256, 0, stream>>>(
          t2, t3, S2, Q2, S3, Q3, z, acc, zi16,
          waccs[s], anexts[s], (s == 0) ? 1 : 0, (s == 3) ? 1 : 0);
    }
  }

  feat_part<<<dim3(B, 4), 256, 0, stream>>>(z, featp);
  head2<<<B, 256, 0, stream>>>(featp, ow, ob, out);
}

// Round 9
// 1797.547 us; speedup vs baseline: 1.4535x; 1.4535x over previous
//
#include <hip/hip_runtime.h>
#include <hip/hip_bf16.h>
#include <cstddef>

// Problem constants
constexpr int B = 128;
constexpr int T = 500;
constexpr int C = 128;     // n_maps
constexpr int CIN = 80;    // n_mels
constexpr int NL = 35;     // labels
constexpr size_t NBCT = (size_t)B * C * T;  // 8,192,000 floats
constexpr int WPAD = 132;                   // LDS i-stride (conflict-free)
constexpr int I0 = 96;                      // conv0 padded input channels
constexpr int IPAD0 = 104;                  // conv0 LDS i-stride
constexpr int NT = 64;                      // conv t-tile
constexpr int NPART = 1024;                 // per-block partial-stats stride

typedef __attribute__((ext_vector_type(8))) _Float16 half8;  // 8 fp16 = 4 VGPR
typedef __attribute__((ext_vector_type(4))) _Float16 half4;
typedef __attribute__((ext_vector_type(4))) float f32x4;

// Static device scratch. Activations in [b][t][c] layout.
__device__ float g_z[NBCT];          // RK4 state (fp32)
__device__ float g_acc[NBCT];        // RK4 k-accumulator (fp32)
__device__ _Float16 g_zi16[NBCT];    // conv input snapshot (fp16)
__device__ _Float16 g_t1[NBCT];      // conv1 out (fp16, pre-BN)
__device__ _Float16 g_t2[NBCT];      // conv2 out (fp16, pre-BN)
__device__ _Float16 g_t3[NBCT];      // conv3 out (fp16, pre-BN)
// Per-block partial stats (no atomics): [c][part]
__device__ float g_ps1[C * NPART], g_pq1[C * NPART];
__device__ float g_ps2[C * NPART], g_pq2[C * NPART];
__device__ float g_ps3[C * NPART], g_pq3[C * NPART];
__device__ float g_m1[C], g_r1[C], g_m2[C], g_r2[C], g_m3[C], g_r3[C];
__device__ float g_featp[B * 4 * C];              // head partial sums
// conv0 weights, layout [kw][o][i] (i-stride I0), fp16
__device__ _Float16 g_w0f[3 * C * I0];
// main conv weights, MFMA-native layout [kw][kseg=i>>3][o][j=i&7], fp16
__device__ _Float16 g_w1f[9 * C * C];
__device__ _Float16 g_w2f[9 * C * C];
__device__ _Float16 g_w3f[1 * C * C];

__device__ inline half8 h8zero() {
  half8 v;
#pragma unroll
  for (int j = 0; j < 8; j++) v[j] = (_Float16)0.f;
  return v;
}

__inline__ __device__ float wave_sum(float v) {
  for (int off = 32; off; off >>= 1) v += __shfl_down(v, off);
  return v;
}

// ---------------------------------------------------------------------------
// Weight prep: w [O][I][KW] fp32 -> fp16, layout [kw][i>>3][o][i&7]
// ---------------------------------------------------------------------------
template <int KW>
__global__ __launch_bounds__(256) void prep_weights_f16(
    const float* __restrict__ w, _Float16* __restrict__ wf) {
  int idx = blockIdx.x * 256 + threadIdx.x;
  if (idx >= C * C * KW) return;
  int kw = idx % KW;
  int i = (idx / KW) % C;
  int o = idx / (KW * C);
  size_t dst = (((size_t)kw * 16 + (i >> 3)) * C + o) * 8 + (i & 7);
  wf[dst] = (_Float16)w[idx];
}

// conv0 weights: w0 [O=128][I=80][3] -> [3][O][I0=96] fp16 (zero-padded i>=80)
__global__ __launch_bounds__(256) void prep_w0_f16(
    const float* __restrict__ w, _Float16* __restrict__ wf) {
  int idx = blockIdx.x * 256 + threadIdx.x;
  if (idx >= 3 * C * I0) return;
  int i = idx % I0;
  int o = (idx / I0) % C;
  int kw = idx / (I0 * C);
  float v = 0.f;
  if (i < CIN) v = w[((size_t)o * CIN + i) * 3 + kw];
  wf[((size_t)kw * C + o) * I0 + i] = (_Float16)v;
}

// ---------------------------------------------------------------------------
// Reduce partials -> mean, rstd per channel (R0-proven).
// ---------------------------------------------------------------------------
__device__ inline void reduce_one(const float* __restrict__ ps,
                                  const float* __restrict__ pq,
                                  float* __restrict__ om,
                                  float* __restrict__ orr, int c) {
  float s = 0.f, q = 0.f;
  for (int p = threadIdx.x; p < NPART; p += 256) {
    s += ps[c * NPART + p];
    q += pq[c * NPART + p];
  }
  s = wave_sum(s);
  q = wave_sum(q);
  __shared__ float ls[8];
  int wv = threadIdx.x >> 6, ln = threadIdx.x & 63;
  if (ln == 0) { ls[wv] = s; ls[4 + wv] = q; }
  __syncthreads();
  if (threadIdx.x == 0) {
    float S = ls[0] + ls[1] + ls[2] + ls[3];
    float Q = ls[4] + ls[5] + ls[6] + ls[7];
    const float invn = 1.f / 64000.f;
    float m = S * invn;
    float v = Q * invn - m * m;
    om[c] = m;
    orr[c] = rsqrtf(v + 1e-5f);
  }
}

__global__ __launch_bounds__(256) void reduce_stats(
    const float* __restrict__ ps, const float* __restrict__ pq,
    float* __restrict__ om, float* __restrict__ orr) {
  reduce_one(ps, pq, om, orr, blockIdx.x);
}

__global__ __launch_bounds__(256) void reduce_stats2(
    const float* __restrict__ psA, const float* __restrict__ pqA,
    float* __restrict__ omA, float* __restrict__ orA,
    const float* __restrict__ psB, const float* __restrict__ pqB,
    float* __restrict__ omB, float* __restrict__ orB) {
  if (blockIdx.y == 0)
    reduce_one(psA, pqA, omA, orA, blockIdx.x);
  else
    reduce_one(psB, pqB, omB, orB, blockIdx.x);
}

// ---------------------------------------------------------------------------
// Epilogues: store D tiles (fp32 or fp16 out) + per-channel partial stats
// into LDS ssum/ssq (LDS atomics only — globals are plain per-block stores).
// D layout (16x16x32): col(t)=lane&15, row(o)=quad*4+reg.
// ---------------------------------------------------------------------------
template <int NG, int NTG>
__device__ inline void store_and_stats_f(f32x4 (&dacc)[NG][NTG],
                                         float* __restrict__ outb,
                                         float* __restrict__ ssum,
                                         float* __restrict__ ssq, int tbase,
                                         int og0, int quad, int m15) {
#pragma unroll
  for (int g = 0; g < NG; g++) {
    float rs[4] = {0.f, 0.f, 0.f, 0.f}, rq[4] = {0.f, 0.f, 0.f, 0.f};
#pragma unroll
    for (int tg = 0; tg < NTG; tg++) {
      int t = tbase + tg * 16 + m15;
      bool valid = t < T;
      f32x4 d = dacc[g][tg];
      if (valid)
        *(f32x4*)(outb + (size_t)t * C + (og0 + g) * 16 + quad * 4) = d;
#pragma unroll
      for (int r = 0; r < 4; r++) {
        float v = valid ? d[r] : 0.f;
        rs[r] += v;
        rq[r] += v * v;
      }
    }
#pragma unroll
    for (int sh = 1; sh < 16; sh <<= 1) {
#pragma unroll
      for (int r = 0; r < 4; r++) {
        rs[r] += __shfl_xor(rs[r], sh);
        rq[r] += __shfl_xor(rq[r], sh);
      }
    }
    if (m15 == 0) {
      int o = (og0 + g) * 16 + quad * 4;
#pragma unroll
      for (int r = 0; r < 4; r++) {
        atomicAdd(&ssum[o + r], rs[r]);
        atomicAdd(&ssq[o + r], rq[r]);
      }
    }
  }
}

template <int NG, int NTG>
__device__ inline void store_and_stats_h(f32x4 (&dacc)[NG][NTG],
                                         _Float16* __restrict__ outb,
                                         float* __restrict__ ssum,
                                         float* __restrict__ ssq, int tbase,
                                         int og0, int quad, int m15) {
#pragma unroll
  for (int g = 0; g < NG; g++) {
    float rs[4] = {0.f, 0.f, 0.f, 0.f}, rq[4] = {0.f, 0.f, 0.f, 0.f};
#pragma unroll
    for (int tg = 0; tg < NTG; tg++) {
      int t = tbase + tg * 16 + m15;
      bool valid = t < T;
      f32x4 d = dacc[g][tg];
      if (valid) {
        half4 h;
#pragma unroll
        for (int r = 0; r < 4; r++) h[r] = (_Float16)d[r];
        *(half4*)(outb + (size_t)t * C + (og0 + g) * 16 + quad * 4) = h;
      }
#pragma unroll
      for (int r = 0; r < 4; r++) {
        float v = valid ? d[r] : 0.f;
        rs[r] += v;
        rq[r] += v * v;
      }
    }
#pragma unroll
    for (int sh = 1; sh < 16; sh <<= 1) {
#pragma unroll
      for (int r = 0; r < 4; r++) {
        rs[r] += __shfl_xor(rs[r], sh);
        rq[r] += __shfl_xor(rq[r], sh);
      }
    }
    if (m15 == 0) {
      int o = (og0 + g) * 16 + quad * 4;
#pragma unroll
      for (int r = 0; r < 4; r++) {
        atomicAdd(&ssum[o + r], rs[r]);
        atomicAdd(&ssq[o + r], rq[r]);
      }
    }
  }
}

// ---------------------------------------------------------------------------
// Fused conv1 (KW=9, PAD=4) + conv3 (KW=1). R4 structure (best measured):
// 512 thr / 8 waves, og0=(wv&3)*2, t-half=(wv>>2)*32, NG=2 x NTG=2,
// fp16 in/out. STATS: per-block partial store (no global atomics) —
// the R1-R7 global-atomic storm (1M same-address atomic ops/dispatch)
// was the hidden ~10-25 us tail under every conv dispatch.
// ---------------------------------------------------------------------------
__global__ __launch_bounds__(512, 8) void conv13(
    const _Float16* __restrict__ in, const _Float16* __restrict__ w9,
    const _Float16* __restrict__ w1, _Float16* __restrict__ out1,
    _Float16* __restrict__ out3, float* __restrict__ ps1,
    float* __restrict__ pq1, float* __restrict__ ps3,
    float* __restrict__ pq3) {
  constexpr int PAD = 4;
  constexpr int ROWS = NT + 8;  // 72
  __shared__ __align__(16) _Float16 sh[ROWS * WPAD];
  __shared__ float ssum1[C], ssq1[C], ssum3[C], ssq3[C];

  const int tid = threadIdx.x;
  const int tile = blockIdx.x;
  const int b = blockIdx.y;
  const int t0 = tile * NT;

  if (tid < 128) {
    ssum1[tid] = 0.f; ssq1[tid] = 0.f;
    ssum3[tid] = 0.f; ssq3[tid] = 0.f;
  }

  // Stage fp16 rows [t0-PAD, t0-PAD+ROWS) — pure copy, 16B loads.
  const _Float16* __restrict__ inb = in + (size_t)b * T * C;
  for (int e = tid; e < ROWS * 16; e += 512) {
    int r = e >> 4;
    int c8 = e & 15;
    int t = t0 - PAD + r;
    half8 v = h8zero();
    if (t >= 0 && t < T) v = *(const half8*)(inb + (size_t)t * C + c8 * 8);
    *(half8*)&sh[r * WPAD + c8 * 8] = v;
  }
  __syncthreads();

  const int wv = tid >> 6;
  const int lane = tid & 63;
  const int quad = lane >> 4;
  const int m15 = lane & 15;
  const int og0 = (wv & 3) * 2;
  const int tr0 = (wv >> 2) * 32;

  const half8* __restrict__ A9 = (const half8*)w9;
  const half8* __restrict__ A1 = (const half8*)w1;

  // --- conv3 (KW=1): 4 rounds, retire accumulator early ---
  {
    f32x4 d3[2][2];
#pragma unroll
    for (int g = 0; g < 2; g++)
#pragma unroll
      for (int tg = 0; tg < 2; tg++) d3[g][tg] = f32x4{0.f, 0.f, 0.f, 0.f};
#pragma unroll
    for (int ic = 0; ic < 4; ic++) {
      const int kof = ic * 32 + quad * 8;
      half8 af[2];
#pragma unroll
      for (int g = 0; g < 2; g++)
        af[g] = A1[(ic * 4 + quad) * C + (og0 + g) * 16 + m15];
      half8 bf[2];
#pragma unroll
      for (int tg = 0; tg < 2; tg++)
        bf[tg] = *(const half8*)(sh + (tr0 + tg * 16 + m15 + PAD) * WPAD + kof);
#pragma unroll
      for (int g = 0; g < 2; g++)
#pragma unroll
        for (int tg = 0; tg < 2; tg++)
          d3[g][tg] = __builtin_amdgcn_mfma_f32_16x16x32_f16(
              af[g], bf[tg], d3[g][tg], 0, 0, 0);
    }
    _Float16* __restrict__ o3b = out3 + (size_t)b * T * C;
    store_and_stats_h<2, 2>(d3, o3b, ssum3, ssq3, t0 + tr0, og0, quad, m15);
  }

  // --- conv1 (KW=9): 36 rounds ---
  f32x4 d1[2][2];
#pragma unroll
  for (int g = 0; g < 2; g++)
#pragma unroll
    for (int tg = 0; tg < 2; tg++) d1[g][tg] = f32x4{0.f, 0.f, 0.f, 0.f};

  for (int kw = 0; kw < 9; kw++) {
#pragma unroll
    for (int ic = 0; ic < 4; ic++) {
      const int kof = ic * 32 + quad * 8;
      half8 af[2];
#pragma unroll
      for (int g = 0; g < 2; g++)
        af[g] = A9[(kw * 16 + ic * 4 + quad) * C + (og0 + g) * 16 + m15];
      half8 bf[2];
#pragma unroll
      for (int tg = 0; tg < 2; tg++)
        bf[tg] = *(const half8*)(sh + (tr0 + tg * 16 + m15 + kw) * WPAD + kof);
#pragma unroll
      for (int g = 0; g < 2; g++)
#pragma unroll
        for (int tg = 0; tg < 2; tg++)
          d1[g][tg] = __builtin_amdgcn_mfma_f32_16x16x32_f16(
              af[g], bf[tg], d1[g][tg], 0, 0, 0);
    }
  }

  _Float16* __restrict__ o1b = out1 + (size_t)b * T * C;
  store_and_stats_h<2, 2>(d1, o1b, ssum1, ssq1, t0 + tr0, og0, quad, m15);
  __syncthreads();
  int p = b * 8 + tile;
  if (tid < 128) {
    ps1[tid * NPART + p] = ssum1[tid];
    pq1[tid * NPART + p] = ssq1[tid];
    ps3[tid * NPART + p] = ssum3[tid];
    pq3[tid * NPART + p] = ssq3[tid];
  }
}

// ---------------------------------------------------------------------------
// conv2 (KW=9, PAD=4): BN+relu on staging from precomputed mean/rstd;
// per-block partial stats store.
// ---------------------------------------------------------------------------
__global__ __launch_bounds__(512, 8) void conv2_bn(
    const _Float16* __restrict__ in, const _Float16* __restrict__ wf,
    const float* __restrict__ bnm, const float* __restrict__ bnr,
    _Float16* __restrict__ out, float* __restrict__ ps,
    float* __restrict__ pq) {
  constexpr int KW = 9, PAD = 4;
  constexpr int ROWS = NT + KW - 1;  // 72
  __shared__ __align__(16) _Float16 sh[ROWS * WPAD];
  __shared__ float ssum[C], ssq[C];
  __shared__ float sbm[C], sbr[C];

  const int tid = threadIdx.x;
  const int tile = blockIdx.x;
  const int b = blockIdx.y;
  const int t0 = tile * NT;

  if (tid < 128) {
    sbm[tid] = bnm[tid];
    sbr[tid] = bnr[tid];
    ssum[tid] = 0.f;
    ssq[tid] = 0.f;
  }
  __syncthreads();  // BN params ready before staging uses them

  const _Float16* __restrict__ inb = in + (size_t)b * T * C;
  for (int e = tid; e < ROWS * 16; e += 512) {
    int r = e >> 4;
    int c8 = e & 15;
    int t = t0 - PAD + r;
    half8 v = h8zero();
    if (t >= 0 && t < T) {
      half8 u = *(const half8*)(inb + (size_t)t * C + c8 * 8);
      int c = c8 * 8;
#pragma unroll
      for (int j = 0; j < 8; j++) {
        float f = (float)u[j];
        f = fmaxf((f - sbm[c + j]) * sbr[c + j], 0.f);
        v[j] = (_Float16)f;
      }
    }
    *(half8*)&sh[r * WPAD + c8 * 8] = v;
  }
  __syncthreads();

  const int wv = tid >> 6;
  const int lane = tid & 63;
  const int quad = lane >> 4;
  const int m15 = lane & 15;
  const int og0 = (wv & 3) * 2;
  const int tr0 = (wv >> 2) * 32;

  const half8* __restrict__ Af = (const half8*)wf;

  f32x4 dacc[2][2];
#pragma unroll
  for (int g = 0; g < 2; g++)
#pragma unroll
    for (int tg = 0; tg < 2; tg++) dacc[g][tg] = f32x4{0.f, 0.f, 0.f, 0.f};

  for (int kw = 0; kw < 9; kw++) {
#pragma unroll
    for (int ic = 0; ic < 4; ic++) {
      const int kof = ic * 32 + quad * 8;
      half8 af[2];
#pragma unroll
      for (int g = 0; g < 2; g++)
        af[g] = Af[(kw * 16 + ic * 4 + quad) * C + (og0 + g) * 16 + m15];
      half8 bf[2];
#pragma unroll
      for (int tg = 0; tg < 2; tg++)
        bf[tg] = *(const half8*)(sh + (tr0 + tg * 16 + m15 + kw) * WPAD + kof);
#pragma unroll
      for (int g = 0; g < 2; g++)
#pragma unroll
        for (int tg = 0; tg < 2; tg++)
          dacc[g][tg] = __builtin_amdgcn_mfma_f32_16x16x32_f16(
              af[g], bf[tg], dacc[g][tg], 0, 0, 0);
    }
  }

  _Float16* __restrict__ outb = out + (size_t)b * T * C;
  store_and_stats_h<2, 2>(dacc, outb, ssum, ssq, t0 + tr0, og0, quad, m15);
  __syncthreads();
  int p = b * 8 + tile;
  if (tid < 128) {
    ps[tid * NPART + p] = ssum[tid];
    pq[tid * NPART + p] = ssq[tid];
  }
}

// ---------------------------------------------------------------------------
// conv0: single fp16 16x16x32 MFMA. in x[B][80][T] (t fastest), K=96(pad) x 3.
// Output z fp32 (state); per-block partial stats.
// ---------------------------------------------------------------------------
__global__ __launch_bounds__(256) void conv0_mfma(
    const float* __restrict__ in, const _Float16* __restrict__ wf,
    float* __restrict__ out, float* __restrict__ ps, float* __restrict__ pq) {
  constexpr int KW = 3, PAD = 1;
  constexpr int ROWS = NT + KW - 1;  // 66
  __shared__ __align__(16) _Float16 sh[ROWS * IPAD0];
  __shared__ float ssum[C], ssq[C];

  const int tid = threadIdx.x;
  const int tile = blockIdx.x;
  const int b = blockIdx.y;
  const int t0 = tile * NT;

  if (tid < 128) { ssum[tid] = 0.f; ssq[tid] = 0.f; }
  __syncthreads();

  const float* __restrict__ inb = in + (size_t)b * CIN * T;
  for (int e = tid; e < I0 * ROWS; e += 256) {
    int i = e / ROWS;
    int r = e % ROWS;
    int t = t0 - PAD + r;
    float v = 0.f;
    if (i < CIN && t >= 0 && t < T) v = inb[(size_t)i * T + t];
    sh[r * IPAD0 + i] = (_Float16)v;
  }
  __syncthreads();

  const int wv = tid >> 6;
  const int lane = tid & 63;
  const int quad = lane >> 4;
  const int m15 = lane & 15;
  const int og0 = wv * 2;

  f32x4 dacc[2][4];
#pragma unroll
  for (int g = 0; g < 2; g++)
#pragma unroll
    for (int tg = 0; tg < 4; tg++) dacc[g][tg] = f32x4{0.f, 0.f, 0.f, 0.f};

  for (int kw = 0; kw < KW; kw++) {
    const _Float16* __restrict__ wk = wf + (size_t)kw * C * I0;
#pragma unroll
    for (int ic = 0; ic < 3; ic++) {
      const int kof = ic * 32 + quad * 8;
      half8 af[2];
#pragma unroll
      for (int g = 0; g < 2; g++) {
        size_t off = (size_t)((og0 + g) * 16 + m15) * I0 + kof;
        af[g] = *(const half8*)(wk + off);
      }
      half8 bf[4];
#pragma unroll
      for (int tg = 0; tg < 4; tg++) {
        int off = (tg * 16 + m15 + kw) * IPAD0 + kof;
        bf[tg] = *(const half8*)(sh + off);
      }
#pragma unroll
      for (int g = 0; g < 2; g++)
#pragma unroll
        for (int tg = 0; tg < 4; tg++)
          dacc[g][tg] = __builtin_amdgcn_mfma_f32_16x16x32_f16(
              af[g], bf[tg], dacc[g][tg], 0, 0, 0);
    }
  }

  float* __restrict__ outb = out + (size_t)b * T * C;
  store_and_stats_f<2, 4>(dacc, outb, ssum, ssq, t0, og0, quad, m15);
  __syncthreads();
  int p = b * 8 + tile;
  if (tid < 128) {
    ps[tid * NPART + p] = ssum[tid];
    pq[tid * NPART + p] = ssq[tid];
  }
}

// ---------------------------------------------------------------------------
// z = relu((z - m[c]) * r[c]) in place (fp32) + fp16 snapshot for conv13.
// ---------------------------------------------------------------------------
__global__ __launch_bounds__(256) void apply_bn_relu(
    float* __restrict__ x, const float* __restrict__ m,
    const float* __restrict__ r, _Float16* __restrict__ zh) {
  __shared__ float sm[C], sr[C];
  if (threadIdx.x < 128) {
    sm[threadIdx.x] = m[threadIdx.x];
    sr[threadIdx.x] = r[threadIdx.x];
  }
  __syncthreads();
  const size_t total4 = NBCT / 4;
  size_t stride = (size_t)gridDim.x * 256;
  for (size_t i4 = (size_t)blockIdx.x * 256 + threadIdx.x; i4 < total4;
       i4 += stride) {
    int c = (int)((i4 & 31) * 4);
    float4 v = ((float4*)x)[i4];
    v.x = fmaxf((v.x - sm[c]) * sr[c], 0.f);
    v.y = fmaxf((v.y - sm[c + 1]) * sr[c + 1], 0.f);
    v.z = fmaxf((v.z - sm[c + 2]) * sr[c + 2], 0.f);
    v.w = fmaxf((v.w - sm[c + 3]) * sr[c + 3], 0.f);
    ((float4*)x)[i4] = v;
    half4 h;
    h[0] = (_Float16)v.x;
    h[1] = (_Float16)v.y;
    h[2] = (_Float16)v.z;
    h[3] = (_Float16)v.w;
    *(half4*)(zh + i4 * 4) = h;
  }
}

// ---------------------------------------------------------------------------
// combine: k = relu(bn2(t2) + relu(bn3(t3))); RK4 update.
// t2/t3 fp16; z/acc fp32; zi16 (fp16 next-conv input) always written;
// z (fp32 state) written only on fin. Uses precomputed mean/rstd.
// ---------------------------------------------------------------------------
__global__ __launch_bounds__(256) void combine_kernel(
    const _Float16* __restrict__ t2, const _Float16* __restrict__ t3,
    const float* __restrict__ m2, const float* __restrict__ r2,
    const float* __restrict__ m3, const float* __restrict__ r3,
    float* __restrict__ z, float* __restrict__ acc,
    _Float16* __restrict__ zi16, float wacc, float anext, int init, int fin) {
  __shared__ float sm2[C], sr2[C], sm3[C], sr3[C];
  if (threadIdx.x < 128) {
    sm2[threadIdx.x] = m2[threadIdx.x];
    sr2[threadIdx.x] = r2[threadIdx.x];
    sm3[threadIdx.x] = m3[threadIdx.x];
    sr3[threadIdx.x] = r3[threadIdx.x];
  }
  __syncthreads();
  const size_t total4 = NBCT / 4;
  size_t stride = (size_t)gridDim.x * 256;
  for (size_t i4 = (size_t)blockIdx.x * 256 + threadIdx.x; i4 < total4;
       i4 += stride) {
    int c = (int)((i4 & 31) * 4);
    size_t off = i4 * 4;
    half4 h2 = *(const half4*)(t2 + off);
    half4 h3 = *(const half4*)(t3 + off);
    float4 vz = *(const float4*)(z + off);
    float k[4];
#pragma unroll
    for (int j = 0; j < 4; j++) {
      float f2 = (float)h2[j];
      float f3 = (float)h3[j];
      k[j] = fmaxf((f2 - sm2[c + j]) * sr2[c + j] +
                       fmaxf((f3 - sm3[c + j]) * sr3[c + j], 0.f),
                   0.f);
    }
    float va[4];
    if (init) {
#pragma unroll
      for (int j = 0; j < 4; j++) va[j] = wacc * k[j];
    } else {
      float4 a = *(const float4*)(acc + off);
      va[0] = a.x + wacc * k[0];
      va[1] = a.y + wacc * k[1];
      va[2] = a.z + wacc * k[2];
      va[3] = a.w + wacc * k[3];
    }
    float vzf[4] = {vz.x, vz.y, vz.z, vz.w};
    float vo[4];
    if (fin) {
#pragma unroll
      for (int j = 0; j < 4; j++) vo[j] = vzf[j] + anext * va[j];
      float4 w4 = make_float4(vo[0], vo[1], vo[2], vo[3]);
      *(float4*)(z + off) = w4;
    } else {
      float4 a4 = make_float4(va[0], va[1], va[2], va[3]);
      *(float4*)(acc + off) = a4;
#pragma unroll
      for (int j = 0; j < 4; j++) vo[j] = vzf[j] + anext * k[j];
    }
    half4 ho;
#pragma unroll
    for (int j = 0; j < 4; j++) ho[j] = (_Float16)vo[j];
    *(half4*)(zi16 + off) = ho;
  }
}

// ---------------------------------------------------------------------------
// head, phase 1: partial t-sums. grid (B, 4), each block sums 125 t's.
// ---------------------------------------------------------------------------
__global__ __launch_bounds__(256) void feat_part(
    const float* __restrict__ z, float* __restrict__ fp) {
  const int b = blockIdx.x;
  const int s = blockIdx.y;
  const int c = threadIdx.x & 127;
  const int h = threadIdx.x >> 7;
  const float* zb = z + (size_t)b * T * C;
  float sum = 0.f;
  for (int t = s * 125 + h; t < (s + 1) * 125; t += 2)
    sum += zb[(size_t)t * C + c];
  __shared__ float sf[2][C];
  sf[h][c] = sum;
  __syncthreads();
  if (threadIdx.x < 128)
    fp[((size_t)b * 4 + s) * C + threadIdx.x] =
        sf[0][threadIdx.x] + sf[1][threadIdx.x];
}

// head, phase 2: feat = sum(partials)/500; out = feat @ ow^T + ob.
__global__ __launch_bounds__(256) void head2(
    const float* __restrict__ fp, const float* __restrict__ ow,
    const float* __restrict__ ob, float* __restrict__ out) {
  const int b = blockIdx.x;
  __shared__ float feat[C];
  if (threadIdx.x < 128) {
    float s = 0.f;
#pragma unroll
    for (int p = 0; p < 4; p++) s += fp[((size_t)b * 4 + p) * C + threadIdx.x];
    feat[threadIdx.x] = s * (1.f / 500.f);
  }
  __syncthreads();
  if (threadIdx.x < NL) {
    int l = threadIdx.x;
    float o = ob[l];
    for (int j = 0; j < C; j++) o = fmaf(feat[j], ow[l * C + j], o);
    out[b * NL + l] = o;
  }
}

// ---------------------------------------------------------------------------
extern "C" void kernel_launch(void* const* d_in, const int* in_sizes, int n_in,
                              void* d_out, int out_size, void* d_ws,
                              size_t ws_size, hipStream_t stream) {
  const float* x  = (const float*)d_in[0];
  const float* w0 = (const float*)d_in[1];
  const float* w1 = (const float*)d_in[2];
  const float* w2 = (const float*)d_in[3];
  const float* w3 = (const float*)d_in[4];
  const float* ow = (const float*)d_in[5];
  const float* ob = (const float*)d_in[6];
  float* out = (float*)d_out;

  static float *z, *acc, *featp;
  static float *ps1, *pq1, *ps2, *pq2, *ps3, *pq3;
  static float *m1, *r1, *m2, *r2, *m3, *r3;
  static _Float16 *zi16, *t1, *t2, *t3;
  static _Float16 *w0f, *w1f, *w2f, *w3f;
  static bool inited = false;
  if (!inited) {
    void* p;
#define GET(sym, var) hipGetSymbolAddress(&p, HIP_SYMBOL(sym)); var = (decltype(var))p;
    GET(g_z, z) GET(g_acc, acc) GET(g_zi16, zi16)
    GET(g_t1, t1) GET(g_t2, t2) GET(g_t3, t3)
    GET(g_ps1, ps1) GET(g_pq1, pq1) GET(g_ps2, ps2) GET(g_pq2, pq2)
    GET(g_ps3, ps3) GET(g_pq3, pq3)
    GET(g_m1, m1) GET(g_r1, r1) GET(g_m2, m2) GET(g_r2, r2)
    GET(g_m3, m3) GET(g_r3, r3) GET(g_featp, featp)
    GET(g_w0f, w0f) GET(g_w1f, w1f) GET(g_w2f, w2f) GET(g_w3f, w3f)
#undef GET
    inited = true;
  }

  // Weight prep (cheap, every launch)
  prep_w0_f16<<<(3 * C * I0 + 255) / 256, 256, 0, stream>>>(w0, w0f);
  prep_weights_f16<9><<<(C * C * 9 + 255) / 256, 256, 0, stream>>>(w1, w1f);
  prep_weights_f16<9><<<(C * C * 9 + 255) / 256, 256, 0, stream>>>(w2, w2f);
  prep_weights_f16<1><<<(C * C * 1 + 255) / 256, 256, 0, stream>>>(w3, w3f);

  const dim3 convGrid(8, B);   // NT=64 tiles -> 1024 blocks of 512 thr
  const int ewGrid = 1024;
  const float dt = 0.25f;

  // conv0 -> reduce -> bn+relu (into z fp32 + zi16 fp16).
  conv0_mfma<<<dim3(8, B), 256, 0, stream>>>(x, w0f, z, ps1, pq1);
  reduce_stats<<<C, 256, 0, stream>>>(ps1, pq1, m1, r1);
  apply_bn_relu<<<ewGrid, 256, 0, stream>>>(z, m1, r1, zi16);

  const float waccs[4] = {1.f, 2.f, 2.f, 1.f};
  const float anexts[4] = {0.5f * dt, 0.5f * dt, dt, dt / 6.f};

  for (int step = 0; step < 4; step++) {
    for (int s = 0; s < 4; s++) {
      conv13<<<convGrid, 512, 0, stream>>>(
          zi16, w1f, w3f, t1, t3, ps1, pq1, ps3, pq3);
      reduce_stats2<<<dim3(C, 2), 256, 0, stream>>>(
          ps1, pq1, m1, r1, ps3, pq3, m3, r3);
      conv2_bn<<<convGrid, 512, 0, stream>>>(
          t1, w2f, m1, r1, t2, ps2, pq2);
      reduce_stats<<<C, 256, 0, stream>>>(ps2, pq2, m2, r2);
      combine_kernel<<<ewGrid, 256, 0, stream>>>(
          t2, t3, m2, r2, m3, r3, z, acc, zi16,
          waccs[s], anexts[s], (s == 0) ? 1 : 0, (s == 3) ? 1 : 0);
    }
  }

  feat_part<<<dim3(B, 4), 256, 0, stream>>>(z, featp);
  head2<<<B, 256, 0, stream>>>(featp, ow, ob, out);
}

// Round 10
// 1604.621 us; speedup vs baseline: 1.6283x; 1.1202x over previous
//
#include <hip/hip_runtime.h>
#include <hip/hip_bf16.h>
#include <cstddef>

// Problem constants
constexpr int B = 128;
constexpr int T = 500;
constexpr int C = 128;     // n_maps
constexpr int CIN = 80;    // n_mels
constexpr int NL = 35;     // labels
constexpr size_t NBCT = (size_t)B * C * T;  // 8,192,000 floats
constexpr int WPAD = 132;                   // LDS i-stride (conflict-free)
constexpr int I0 = 96;                      // conv0 padded input channels
constexpr int IPAD0 = 104;                  // conv0 LDS i-stride
constexpr int NT = 64;                      // conv t-tile
constexpr int NPART = 1024;                 // per-block partial-stats stride

typedef __attribute__((ext_vector_type(8))) _Float16 half8;  // 8 fp16 = 4 VGPR
typedef __attribute__((ext_vector_type(4))) _Float16 half4;
typedef __attribute__((ext_vector_type(4))) float f32x4;

// Static device scratch. Activations in [b][t][c] layout.
__device__ float g_z[NBCT];          // RK4 state (fp32)
__device__ _Float16 g_acc16[NBCT];   // RK4 k-accumulator (fp16)
__device__ _Float16 g_zi16[NBCT];    // conv input snapshot (fp16)
__device__ _Float16 g_t1[NBCT];      // conv1 out (fp16, pre-BN)
__device__ _Float16 g_t2[NBCT];      // conv2 out (fp16, pre-BN)
__device__ _Float16 g_t3[NBCT];      // conv3 out (fp16, pre-BN)
// Per-block partial stats (no atomics): [c][part]
__device__ float g_ps1[C * NPART], g_pq1[C * NPART];
__device__ float g_ps2[C * NPART], g_pq2[C * NPART];
__device__ float g_ps3[C * NPART], g_pq3[C * NPART];
__device__ float g_m1[C], g_r1[C], g_m2[C], g_r2[C], g_m3[C], g_r3[C];
__device__ float g_featp[B * 4 * C];              // head partial sums
// conv0 weights, layout [kw][o][i] (i-stride I0), fp16
__device__ _Float16 g_w0f[3 * C * I0];
// main conv weights, MFMA-native layout [kw][kseg=i>>3][o][j=i&7], fp16
__device__ _Float16 g_w1f[9 * C * C];
__device__ _Float16 g_w2f[9 * C * C];
__device__ _Float16 g_w3f[1 * C * C];

__device__ inline half8 h8zero() {
  half8 v;
#pragma unroll
  for (int j = 0; j < 8; j++) v[j] = (_Float16)0.f;
  return v;
}

__inline__ __device__ float wave_sum(float v) {
  for (int off = 32; off; off >>= 1) v += __shfl_down(v, off);
  return v;
}

// ---------------------------------------------------------------------------
// Weight prep: w [O][I][KW] fp32 -> fp16, layout [kw][i>>3][o][i&7]
// ---------------------------------------------------------------------------
template <int KW>
__global__ __launch_bounds__(256) void prep_weights_f16(
    const float* __restrict__ w, _Float16* __restrict__ wf) {
  int idx = blockIdx.x * 256 + threadIdx.x;
  if (idx >= C * C * KW) return;
  int kw = idx % KW;
  int i = (idx / KW) % C;
  int o = idx / (KW * C);
  size_t dst = (((size_t)kw * 16 + (i >> 3)) * C + o) * 8 + (i & 7);
  wf[dst] = (_Float16)w[idx];
}

// conv0 weights: w0 [O=128][I=80][3] -> [3][O][I0=96] fp16 (zero-padded i>=80)
__global__ __launch_bounds__(256) void prep_w0_f16(
    const float* __restrict__ w, _Float16* __restrict__ wf) {
  int idx = blockIdx.x * 256 + threadIdx.x;
  if (idx >= 3 * C * I0) return;
  int i = idx % I0;
  int o = (idx / I0) % C;
  int kw = idx / (I0 * C);
  float v = 0.f;
  if (i < CIN) v = w[((size_t)o * CIN + i) * 3 + kw];
  wf[((size_t)kw * C + o) * I0 + i] = (_Float16)v;
}

// ---------------------------------------------------------------------------
// Reduce partials -> mean, rstd per channel.
// ---------------------------------------------------------------------------
__device__ inline void reduce_one(const float* __restrict__ ps,
                                  const float* __restrict__ pq,
                                  float* __restrict__ om,
                                  float* __restrict__ orr, int c) {
  float s = 0.f, q = 0.f;
  for (int p = threadIdx.x; p < NPART; p += 256) {
    s += ps[c * NPART + p];
    q += pq[c * NPART + p];
  }
  s = wave_sum(s);
  q = wave_sum(q);
  __shared__ float ls[8];
  int wv = threadIdx.x >> 6, ln = threadIdx.x & 63;
  if (ln == 0) { ls[wv] = s; ls[4 + wv] = q; }
  __syncthreads();
  if (threadIdx.x == 0) {
    float S = ls[0] + ls[1] + ls[2] + ls[3];
    float Q = ls[4] + ls[5] + ls[6] + ls[7];
    const float invn = 1.f / 64000.f;
    float m = S * invn;
    float v = Q * invn - m * m;
    om[c] = m;
    orr[c] = rsqrtf(v + 1e-5f);
  }
}

__global__ __launch_bounds__(256) void reduce_stats(
    const float* __restrict__ ps, const float* __restrict__ pq,
    float* __restrict__ om, float* __restrict__ orr) {
  reduce_one(ps, pq, om, orr, blockIdx.x);
}

__global__ __launch_bounds__(256) void reduce_stats2(
    const float* __restrict__ psA, const float* __restrict__ pqA,
    float* __restrict__ omA, float* __restrict__ orA,
    const float* __restrict__ psB, const float* __restrict__ pqB,
    float* __restrict__ omB, float* __restrict__ orB) {
  if (blockIdx.y == 0)
    reduce_one(psA, pqA, omA, orA, blockIdx.x);
  else
    reduce_one(psB, pqB, omB, orB, blockIdx.x);
}

// ---------------------------------------------------------------------------
// Epilogues: store D tiles (fp32 or fp16 out) + per-channel partial stats
// into LDS ssum/ssq (LDS atomics only — globals are plain per-block stores).
// D layout (16x16x32): col(t)=lane&15, row(o)=quad*4+reg.
// ---------------------------------------------------------------------------
template <int NG, int NTG>
__device__ inline void store_and_stats_f(f32x4 (&dacc)[NG][NTG],
                                         float* __restrict__ outb,
                                         float* __restrict__ ssum,
                                         float* __restrict__ ssq, int tbase,
                                         int og0, int quad, int m15) {
#pragma unroll
  for (int g = 0; g < NG; g++) {
    float rs[4] = {0.f, 0.f, 0.f, 0.f}, rq[4] = {0.f, 0.f, 0.f, 0.f};
#pragma unroll
    for (int tg = 0; tg < NTG; tg++) {
      int t = tbase + tg * 16 + m15;
      bool valid = t < T;
      f32x4 d = dacc[g][tg];
      if (valid)
        *(f32x4*)(outb + (size_t)t * C + (og0 + g) * 16 + quad * 4) = d;
#pragma unroll
      for (int r = 0; r < 4; r++) {
        float v = valid ? d[r] : 0.f;
        rs[r] += v;
        rq[r] += v * v;
      }
    }
#pragma unroll
    for (int sh = 1; sh < 16; sh <<= 1) {
#pragma unroll
      for (int r = 0; r < 4; r++) {
        rs[r] += __shfl_xor(rs[r], sh);
        rq[r] += __shfl_xor(rq[r], sh);
      }
    }
    if (m15 == 0) {
      int o = (og0 + g) * 16 + quad * 4;
#pragma unroll
      for (int r = 0; r < 4; r++) {
        atomicAdd(&ssum[o + r], rs[r]);
        atomicAdd(&ssq[o + r], rq[r]);
      }
    }
  }
}

template <int NG, int NTG>
__device__ inline void store_and_stats_h(f32x4 (&dacc)[NG][NTG],
                                         _Float16* __restrict__ outb,
                                         float* __restrict__ ssum,
                                         float* __restrict__ ssq, int tbase,
                                         int og0, int quad, int m15) {
#pragma unroll
  for (int g = 0; g < NG; g++) {
    float rs[4] = {0.f, 0.f, 0.f, 0.f}, rq[4] = {0.f, 0.f, 0.f, 0.f};
#pragma unroll
    for (int tg = 0; tg < NTG; tg++) {
      int t = tbase + tg * 16 + m15;
      bool valid = t < T;
      f32x4 d = dacc[g][tg];
      if (valid) {
        half4 h;
#pragma unroll
        for (int r = 0; r < 4; r++) h[r] = (_Float16)d[r];
        *(half4*)(outb + (size_t)t * C + (og0 + g) * 16 + quad * 4) = h;
      }
#pragma unroll
      for (int r = 0; r < 4; r++) {
        float v = valid ? d[r] : 0.f;
        rs[r] += v;
        rq[r] += v * v;
      }
    }
#pragma unroll
    for (int sh = 1; sh < 16; sh <<= 1) {
#pragma unroll
      for (int r = 0; r < 4; r++) {
        rs[r] += __shfl_xor(rs[r], sh);
        rq[r] += __shfl_xor(rq[r], sh);
      }
    }
    if (m15 == 0) {
      int o = (og0 + g) * 16 + quad * 4;
#pragma unroll
      for (int r = 0; r < 4; r++) {
        atomicAdd(&ssum[o + r], rs[r]);
        atomicAdd(&ssq[o + r], rq[r]);
      }
    }
  }
}

// ---------------------------------------------------------------------------
// Fused conv1 (KW=9, PAD=4) + conv3 (KW=1). R9 + MINIMAL-A geometry:
// 256 thr / 4 waves, og0 = wv*2 (each wave a distinct o-pair, all 8 groups
// covered once -> per-block A-traffic 640 -> 320 KB = the minimum), NTG=4
// (full t-range per wave). 4 blocks/CU = 16 waves/CU. Stats via per-block
// partial stores (R9's proven fix).
// ---------------------------------------------------------------------------
__global__ __launch_bounds__(256, 4) void conv13(
    const _Float16* __restrict__ in, const _Float16* __restrict__ w9,
    const _Float16* __restrict__ w1, _Float16* __restrict__ out1,
    _Float16* __restrict__ out3, float* __restrict__ ps1,
    float* __restrict__ pq1, float* __restrict__ ps3,
    float* __restrict__ pq3) {
  constexpr int PAD = 4;
  constexpr int ROWS = NT + 8;  // 72
  __shared__ __align__(16) _Float16 sh[ROWS * WPAD];
  __shared__ float ssum1[C], ssq1[C], ssum3[C], ssq3[C];

  const int tid = threadIdx.x;
  const int tile = blockIdx.x;
  const int b = blockIdx.y;
  const int t0 = tile * NT;

  if (tid < 128) {
    ssum1[tid] = 0.f; ssq1[tid] = 0.f;
    ssum3[tid] = 0.f; ssq3[tid] = 0.f;
  }

  // Stage fp16 rows [t0-PAD, t0-PAD+ROWS) — pure copy, 16B loads.
  const _Float16* __restrict__ inb = in + (size_t)b * T * C;
  for (int e = tid; e < ROWS * 16; e += 256) {
    int r = e >> 4;
    int c8 = e & 15;
    int t = t0 - PAD + r;
    half8 v = h8zero();
    if (t >= 0 && t < T) v = *(const half8*)(inb + (size_t)t * C + c8 * 8);
    *(half8*)&sh[r * WPAD + c8 * 8] = v;
  }
  __syncthreads();

  const int wv = tid >> 6;
  const int lane = tid & 63;
  const int quad = lane >> 4;
  const int m15 = lane & 15;
  const int og0 = wv * 2;  // waves own disjoint o-pairs: no A duplication

  const half8* __restrict__ A9 = (const half8*)w9;
  const half8* __restrict__ A1 = (const half8*)w1;

  // --- conv3 (KW=1): 4 rounds, retire accumulator early ---
  {
    f32x4 d3[2][4];
#pragma unroll
    for (int g = 0; g < 2; g++)
#pragma unroll
      for (int tg = 0; tg < 4; tg++) d3[g][tg] = f32x4{0.f, 0.f, 0.f, 0.f};
#pragma unroll
    for (int ic = 0; ic < 4; ic++) {
      const int kof = ic * 32 + quad * 8;
      half8 af[2];
#pragma unroll
      for (int g = 0; g < 2; g++)
        af[g] = A1[(ic * 4 + quad) * C + (og0 + g) * 16 + m15];
      half8 bf[4];
#pragma unroll
      for (int tg = 0; tg < 4; tg++)
        bf[tg] = *(const half8*)(sh + (tg * 16 + m15 + PAD) * WPAD + kof);
#pragma unroll
      for (int g = 0; g < 2; g++)
#pragma unroll
        for (int tg = 0; tg < 4; tg++)
          d3[g][tg] = __builtin_amdgcn_mfma_f32_16x16x32_f16(
              af[g], bf[tg], d3[g][tg], 0, 0, 0);
    }
    _Float16* __restrict__ o3b = out3 + (size_t)b * T * C;
    store_and_stats_h<2, 4>(d3, o3b, ssum3, ssq3, t0, og0, quad, m15);
  }

  // --- conv1 (KW=9): 36 rounds ---
  f32x4 d1[2][4];
#pragma unroll
  for (int g = 0; g < 2; g++)
#pragma unroll
    for (int tg = 0; tg < 4; tg++) d1[g][tg] = f32x4{0.f, 0.f, 0.f, 0.f};

  for (int kw = 0; kw < 9; kw++) {
#pragma unroll
    for (int ic = 0; ic < 4; ic++) {
      const int kof = ic * 32 + quad * 8;
      half8 af[2];
#pragma unroll
      for (int g = 0; g < 2; g++)
        af[g] = A9[(kw * 16 + ic * 4 + quad) * C + (og0 + g) * 16 + m15];
      half8 bf[4];
#pragma unroll
      for (int tg = 0; tg < 4; tg++)
        bf[tg] = *(const half8*)(sh + (tg * 16 + m15 + kw) * WPAD + kof);
#pragma unroll
      for (int g = 0; g < 2; g++)
#pragma unroll
        for (int tg = 0; tg < 4; tg++)
          d1[g][tg] = __builtin_amdgcn_mfma_f32_16x16x32_f16(
              af[g], bf[tg], d1[g][tg], 0, 0, 0);
    }
  }

  _Float16* __restrict__ o1b = out1 + (size_t)b * T * C;
  store_and_stats_h<2, 4>(d1, o1b, ssum1, ssq1, t0, og0, quad, m15);
  __syncthreads();
  int p = b * 8 + tile;
  if (tid < 128) {
    ps1[tid * NPART + p] = ssum1[tid];
    pq1[tid * NPART + p] = ssq1[tid];
    ps3[tid * NPART + p] = ssum3[tid];
    pq3[tid * NPART + p] = ssq3[tid];
  }
}

// ---------------------------------------------------------------------------
// conv2 (KW=9, PAD=4): BN+relu on staging from precomputed mean/rstd;
// minimal-A geometry; per-block partial stats store.
// ---------------------------------------------------------------------------
__global__ __launch_bounds__(256, 4) void conv2_bn(
    const _Float16* __restrict__ in, const _Float16* __restrict__ wf,
    const float* __restrict__ bnm, const float* __restrict__ bnr,
    _Float16* __restrict__ out, float* __restrict__ ps,
    float* __restrict__ pq) {
  constexpr int KW = 9, PAD = 4;
  constexpr int ROWS = NT + KW - 1;  // 72
  __shared__ __align__(16) _Float16 sh[ROWS * WPAD];
  __shared__ float ssum[C], ssq[C];
  __shared__ float sbm[C], sbr[C];

  const int tid = threadIdx.x;
  const int tile = blockIdx.x;
  const int b = blockIdx.y;
  const int t0 = tile * NT;

  if (tid < 128) {
    sbm[tid] = bnm[tid];
    sbr[tid] = bnr[tid];
    ssum[tid] = 0.f;
    ssq[tid] = 0.f;
  }
  __syncthreads();  // BN params ready before staging uses them

  const _Float16* __restrict__ inb = in + (size_t)b * T * C;
  for (int e = tid; e < ROWS * 16; e += 256) {
    int r = e >> 4;
    int c8 = e & 15;
    int t = t0 - PAD + r;
    half8 v = h8zero();
    if (t >= 0 && t < T) {
      half8 u = *(const half8*)(inb + (size_t)t * C + c8 * 8);
      int c = c8 * 8;
#pragma unroll
      for (int j = 0; j < 8; j++) {
        float f = (float)u[j];
        f = fmaxf((f - sbm[c + j]) * sbr[c + j], 0.f);
        v[j] = (_Float16)f;
      }
    }
    *(half8*)&sh[r * WPAD + c8 * 8] = v;
  }
  __syncthreads();

  const int wv = tid >> 6;
  const int lane = tid & 63;
  const int quad = lane >> 4;
  const int m15 = lane & 15;
  const int og0 = wv * 2;

  const half8* __restrict__ Af = (const half8*)wf;

  f32x4 dacc[2][4];
#pragma unroll
  for (int g = 0; g < 2; g++)
#pragma unroll
    for (int tg = 0; tg < 4; tg++) dacc[g][tg] = f32x4{0.f, 0.f, 0.f, 0.f};

  for (int kw = 0; kw < 9; kw++) {
#pragma unroll
    for (int ic = 0; ic < 4; ic++) {
      const int kof = ic * 32 + quad * 8;
      half8 af[2];
#pragma unroll
      for (int g = 0; g < 2; g++)
        af[g] = Af[(kw * 16 + ic * 4 + quad) * C + (og0 + g) * 16 + m15];
      half8 bf[4];
#pragma unroll
      for (int tg = 0; tg < 4; tg++)
        bf[tg] = *(const half8*)(sh + (tg * 16 + m15 + kw) * WPAD + kof);
#pragma unroll
      for (int g = 0; g < 2; g++)
#pragma unroll
        for (int tg = 0; tg < 4; tg++)
          dacc[g][tg] = __builtin_amdgcn_mfma_f32_16x16x32_f16(
              af[g], bf[tg], dacc[g][tg], 0, 0, 0);
    }
  }

  _Float16* __restrict__ outb = out + (size_t)b * T * C;
  store_and_stats_h<2, 4>(dacc, outb, ssum, ssq, t0, og0, quad, m15);
  __syncthreads();
  int p = b * 8 + tile;
  if (tid < 128) {
    ps[tid * NPART + p] = ssum[tid];
    pq[tid * NPART + p] = ssq[tid];
  }
}

// ---------------------------------------------------------------------------
// conv0: single fp16 16x16x32 MFMA. in x[B][80][T] (t fastest), K=96(pad) x 3.
// Output z fp32 (state); per-block partial stats.
// ---------------------------------------------------------------------------
__global__ __launch_bounds__(256) void conv0_mfma(
    const float* __restrict__ in, const _Float16* __restrict__ wf,
    float* __restrict__ out, float* __restrict__ ps, float* __restrict__ pq) {
  constexpr int KW = 3, PAD = 1;
  constexpr int ROWS = NT + KW - 1;  // 66
  __shared__ __align__(16) _Float16 sh[ROWS * IPAD0];
  __shared__ float ssum[C], ssq[C];

  const int tid = threadIdx.x;
  const int tile = blockIdx.x;
  const int b = blockIdx.y;
  const int t0 = tile * NT;

  if (tid < 128) { ssum[tid] = 0.f; ssq[tid] = 0.f; }
  __syncthreads();

  const float* __restrict__ inb = in + (size_t)b * CIN * T;
  for (int e = tid; e < I0 * ROWS; e += 256) {
    int i = e / ROWS;
    int r = e % ROWS;
    int t = t0 - PAD + r;
    float v = 0.f;
    if (i < CIN && t >= 0 && t < T) v = inb[(size_t)i * T + t];
    sh[r * IPAD0 + i] = (_Float16)v;
  }
  __syncthreads();

  const int wv = tid >> 6;
  const int lane = tid & 63;
  const int quad = lane >> 4;
  const int m15 = lane & 15;
  const int og0 = wv * 2;

  f32x4 dacc[2][4];
#pragma unroll
  for (int g = 0; g < 2; g++)
#pragma unroll
    for (int tg = 0; tg < 4; tg++) dacc[g][tg] = f32x4{0.f, 0.f, 0.f, 0.f};

  for (int kw = 0; kw < KW; kw++) {
    const _Float16* __restrict__ wk = wf + (size_t)kw * C * I0;
#pragma unroll
    for (int ic = 0; ic < 3; ic++) {
      const int kof = ic * 32 + quad * 8;
      half8 af[2];
#pragma unroll
      for (int g = 0; g < 2; g++) {
        size_t off = (size_t)((og0 + g) * 16 + m15) * I0 + kof;
        af[g] = *(const half8*)(wk + off);
      }
      half8 bf[4];
#pragma unroll
      for (int tg = 0; tg < 4; tg++) {
        int off = (tg * 16 + m15 + kw) * IPAD0 + kof;
        bf[tg] = *(const half8*)(sh + off);
      }
#pragma unroll
      for (int g = 0; g < 2; g++)
#pragma unroll
        for (int tg = 0; tg < 4; tg++)
          dacc[g][tg] = __builtin_amdgcn_mfma_f32_16x16x32_f16(
              af[g], bf[tg], dacc[g][tg], 0, 0, 0);
    }
  }

  float* __restrict__ outb = out + (size_t)b * T * C;
  store_and_stats_f<2, 4>(dacc, outb, ssum, ssq, t0, og0, quad, m15);
  __syncthreads();
  int p = b * 8 + tile;
  if (tid < 128) {
    ps[tid * NPART + p] = ssum[tid];
    pq[tid * NPART + p] = ssq[tid];
  }
}

// ---------------------------------------------------------------------------
// z = relu((z - m[c]) * r[c]) in place (fp32) + fp16 snapshot for conv13.
// ---------------------------------------------------------------------------
__global__ __launch_bounds__(256) void apply_bn_relu(
    float* __restrict__ x, const float* __restrict__ m,
    const float* __restrict__ r, _Float16* __restrict__ zh) {
  __shared__ float sm[C], sr[C];
  if (threadIdx.x < 128) {
    sm[threadIdx.x] = m[threadIdx.x];
    sr[threadIdx.x] = r[threadIdx.x];
  }
  __syncthreads();
  const size_t total4 = NBCT / 4;
  size_t stride = (size_t)gridDim.x * 256;
  for (size_t i4 = (size_t)blockIdx.x * 256 + threadIdx.x; i4 < total4;
       i4 += stride) {
    int c = (int)((i4 & 31) * 4);
    float4 v = ((float4*)x)[i4];
    v.x = fmaxf((v.x - sm[c]) * sr[c], 0.f);
    v.y = fmaxf((v.y - sm[c + 1]) * sr[c + 1], 0.f);
    v.z = fmaxf((v.z - sm[c + 2]) * sr[c + 2], 0.f);
    v.w = fmaxf((v.w - sm[c + 3]) * sr[c + 3], 0.f);
    ((float4*)x)[i4] = v;
    half4 h;
    h[0] = (_Float16)v.x;
    h[1] = (_Float16)v.y;
    h[2] = (_Float16)v.z;
    h[3] = (_Float16)v.w;
    *(half4*)(zh + i4 * 4) = h;
  }
}

// ---------------------------------------------------------------------------
// combine: k = relu(bn2(t2) + relu(bn3(t3))); RK4 update.
// Grid (8,B) matched to the conv grid: block (tile,b) writes exactly the
// zi16 region conv13 block (tile,b) reads -> same flat block id -> likely
// same XCD L2. acc is fp16 (k magnitudes O(1); saves 32 MB/dispatch).
// ---------------------------------------------------------------------------
__global__ __launch_bounds__(256) void combine_kernel(
    const _Float16* __restrict__ t2, const _Float16* __restrict__ t3,
    const float* __restrict__ m2, const float* __restrict__ r2,
    const float* __restrict__ m3, const float* __restrict__ r3,
    float* __restrict__ z, _Float16* __restrict__ acc,
    _Float16* __restrict__ zi16, float wacc, float anext, int init, int fin) {
  __shared__ float sm2[C], sr2[C], sm3[C], sr3[C];
  if (threadIdx.x < 128) {
    sm2[threadIdx.x] = m2[threadIdx.x];
    sr2[threadIdx.x] = r2[threadIdx.x];
    sm3[threadIdx.x] = m3[threadIdx.x];
    sr3[threadIdx.x] = r3[threadIdx.x];
  }
  __syncthreads();
  const int tile = blockIdx.x;
  const int b = blockIdx.y;
  const int t0 = tile * NT;
  for (int e = threadIdx.x; e < NT * (C / 4); e += 256) {
    int row = e >> 5;
    int c4 = e & 31;
    int t = t0 + row;
    if (t >= T) break;
    size_t off = (size_t)b * T * C + (size_t)t * C + c4 * 4;
    int c = c4 * 4;
    half4 h2 = *(const half4*)(t2 + off);
    half4 h3 = *(const half4*)(t3 + off);
    float4 vz = *(const float4*)(z + off);
    float k[4];
#pragma unroll
    for (int j = 0; j < 4; j++) {
      float f2 = (float)h2[j];
      float f3 = (float)h3[j];
      k[j] = fmaxf((f2 - sm2[c + j]) * sr2[c + j] +
                       fmaxf((f3 - sm3[c + j]) * sr3[c + j], 0.f),
                   0.f);
    }
    float va[4];
    if (init) {
#pragma unroll
      for (int j = 0; j < 4; j++) va[j] = wacc * k[j];
    } else {
      half4 ar = *(const half4*)(acc + off);
#pragma unroll
      for (int j = 0; j < 4; j++) va[j] = (float)ar[j] + wacc * k[j];
    }
    float vzf[4] = {vz.x, vz.y, vz.z, vz.w};
    float vo[4];
    if (fin) {
#pragma unroll
      for (int j = 0; j < 4; j++) vo[j] = vzf[j] + anext * va[j];
      float4 w4 = make_float4(vo[0], vo[1], vo[2], vo[3]);
      *(float4*)(z + off) = w4;
    } else {
      half4 aw;
#pragma unroll
      for (int j = 0; j < 4; j++) aw[j] = (_Float16)va[j];
      *(half4*)(acc + off) = aw;
#pragma unroll
      for (int j = 0; j < 4; j++) vo[j] = vzf[j] + anext * k[j];
    }
    half4 ho;
#pragma unroll
    for (int j = 0; j < 4; j++) ho[j] = (_Float16)vo[j];
    *(half4*)(zi16 + off) = ho;
  }
}

// ---------------------------------------------------------------------------
// head, phase 1: partial t-sums. grid (B, 4), each block sums 125 t's.
// ---------------------------------------------------------------------------
__global__ __launch_bounds__(256) void feat_part(
    const float* __restrict__ z, float* __restrict__ fp) {
  const int b = blockIdx.x;
  const int s = blockIdx.y;
  const int c = threadIdx.x & 127;
  const int h = threadIdx.x >> 7;
  const float* zb = z + (size_t)b * T * C;
  float sum = 0.f;
  for (int t = s * 125 + h; t < (s + 1) * 125; t += 2)
    sum += zb[(size_t)t * C + c];
  __shared__ float sf[2][C];
  sf[h][c] = sum;
  __syncthreads();
  if (threadIdx.x < 128)
    fp[((size_t)b * 4 + s) * C + threadIdx.x] =
        sf[0][threadIdx.x] + sf[1][threadIdx.x];
}

// head, phase 2: feat = sum(partials)/500; out = feat @ ow^T + ob.
__global__ __launch_bounds__(256) void head2(
    const float* __restrict__ fp, const float* __restrict__ ow,
    const float* __restrict__ ob, float* __restrict__ out) {
  const int b = blockIdx.x;
  __shared__ float feat[C];
  if (threadIdx.x < 128) {
    float s = 0.f;
#pragma unroll
    for (int p = 0; p < 4; p++) s += fp[((size_t)b * 4 + p) * C + threadIdx.x];
    feat[threadIdx.x] = s * (1.f / 500.f);
  }
  __syncthreads();
  if (threadIdx.x < NL) {
    int l = threadIdx.x;
    float o = ob[l];
    for (int j = 0; j < C; j++) o = fmaf(feat[j], ow[l * C + j], o);
    out[b * NL + l] = o;
  }
}

// ---------------------------------------------------------------------------
extern "C" void kernel_launch(void* const* d_in, const int* in_sizes, int n_in,
                              void* d_out, int out_size, void* d_ws,
                              size_t ws_size, hipStream_t stream) {
  const float* x  = (const float*)d_in[0];
  const float* w0 = (const float*)d_in[1];
  const float* w1 = (const float*)d_in[2];
  const float* w2 = (const float*)d_in[3];
  const float* w3 = (const float*)d_in[4];
  const float* ow = (const float*)d_in[5];
  const float* ob = (const float*)d_in[6];
  float* out = (float*)d_out;

  static float *z, *featp;
  static float *ps1, *pq1, *ps2, *pq2, *ps3, *pq3;
  static float *m1, *r1, *m2, *r2, *m3, *r3;
  static _Float16 *acc16, *zi16, *t1, *t2, *t3;
  static _Float16 *w0f, *w1f, *w2f, *w3f;
  static bool inited = false;
  if (!inited) {
    void* p;
#define GET(sym, var) hipGetSymbolAddress(&p, HIP_SYMBOL(sym)); var = (decltype(var))p;
    GET(g_z, z) GET(g_acc16, acc16) GET(g_zi16, zi16)
    GET(g_t1, t1) GET(g_t2, t2) GET(g_t3, t3)
    GET(g_ps1, ps1) GET(g_pq1, pq1) GET(g_ps2, ps2) GET(g_pq2, pq2)
    GET(g_ps3, ps3) GET(g_pq3, pq3)
    GET(g_m1, m1) GET(g_r1, r1) GET(g_m2, m2) GET(g_r2, r2)
    GET(g_m3, m3) GET(g_r3, r3) GET(g_featp, featp)
    GET(g_w0f, w0f) GET(g_w1f, w1f) GET(g_w2f, w2f) GET(g_w3f, w3f)
#undef GET
    inited = true;
  }

  // Weight prep (cheap, every launch)
  prep_w0_f16<<<(3 * C * I0 + 255) / 256, 256, 0, stream>>>(w0, w0f);
  prep_weights_f16<9><<<(C * C * 9 + 255) / 256, 256, 0, stream>>>(w1, w1f);
  prep_weights_f16<9><<<(C * C * 9 + 255) / 256, 256, 0, stream>>>(w2, w2f);
  prep_weights_f16<1><<<(C * C * 1 + 255) / 256, 256, 0, stream>>>(w3, w3f);

  const dim3 convGrid(8, B);   // NT=64 tiles -> 1024 blocks of 256 thr
  const int ewGrid = 1024;
  const float dt = 0.25f;

  // conv0 -> reduce -> bn+relu (into z fp32 + zi16 fp16).
  conv0_mfma<<<dim3(8, B), 256, 0, stream>>>(x, w0f, z, ps1, pq1);
  reduce_stats<<<C, 256, 0, stream>>>(ps1, pq1, m1, r1);
  apply_bn_relu<<<ewGrid, 256, 0, stream>>>(z, m1, r1, zi16);

  const float waccs[4] = {1.f, 2.f, 2.f, 1.f};
  const float anexts[4] = {0.5f * dt, 0.5f * dt, dt, dt / 6.f};

  for (int step = 0; step < 4; step++) {
    for (int s = 0; s < 4; s++) {
      conv13<<<convGrid, 256, 0, stream>>>(
          zi16, w1f, w3f, t1, t3, ps1, pq1, ps3, pq3);
      reduce_stats2<<<dim3(C, 2), 256, 0, stream>>>(
          ps1, pq1, m1, r1, ps3, pq3, m3, r3);
      conv2_bn<<<convGrid, 256, 0, stream>>>(
          t1, w2f, m1, r1, t2, ps2, pq2);
      reduce_stats<<<C, 256, 0, stream>>>(ps2, pq2, m2, r2);
      combine_kernel<<<convGrid, 256, 0, stream>>>(
          t2, t3, m2, r2, m3, r3, z, acc16, zi16,
          waccs[s], anexts[s], (s == 0) ? 1 : 0, (s == 3) ? 1 : 0);
    }
  }

  feat_part<<<dim3(B, 4), 256, 0, stream>>>(z, featp);
  head2<<<B, 256, 0, stream>>>(featp, ow, ob, out);
}

// Round 11
// 1462.961 us; speedup vs baseline: 1.7859x; 1.0968x over previous
//
#include <hip/hip_runtime.h>
#include <hip/hip_bf16.h>
#include <cstddef>

// Problem constants
constexpr int B = 128;
constexpr int T = 500;
constexpr int C = 128;     // n_maps
constexpr int CIN = 80;    // n_mels
constexpr int NL = 35;     // labels
constexpr size_t NBCT = (size_t)B * C * T;  // 8,192,000 floats
constexpr int WPAD = 132;                   // LDS i-stride (conflict-free)
constexpr int I0 = 96;                      // conv0 padded input channels
constexpr int IPAD0 = 104;                  // conv0 LDS i-stride
constexpr int NT = 64;                      // conv t-tile
constexpr int NPART = 1024;                 // per-block partial-stats stride

typedef __attribute__((ext_vector_type(8))) _Float16 half8;  // 8 fp16 = 4 VGPR
typedef __attribute__((ext_vector_type(4))) _Float16 half4;
typedef __attribute__((ext_vector_type(4))) float f32x4;

// Static device scratch. Activations in [b][t][c] layout.
__device__ float g_zA[NBCT];         // RK4 state ping (fp32)
__device__ float g_zB[NBCT];         // RK4 state pong (fp32)
__device__ _Float16 g_accA[NBCT];    // RK4 k-accumulator ping (fp16)
__device__ _Float16 g_accB[NBCT];    // RK4 k-accumulator pong (fp16)
__device__ _Float16 g_zi16[NBCT];    // conv input snapshot (fp16, i=0 only)
__device__ _Float16 g_t1[NBCT];      // conv1 out (fp16, pre-BN)
__device__ _Float16 g_t2[NBCT];      // conv2 out (fp16, pre-BN)
__device__ _Float16 g_t3[NBCT];      // conv3 out (fp16, pre-BN)
// Per-block partial stats (no atomics): [c][part]
__device__ float g_ps1[C * NPART], g_pq1[C * NPART];
__device__ float g_ps2[C * NPART], g_pq2[C * NPART];
__device__ float g_ps3[C * NPART], g_pq3[C * NPART];
__device__ float g_m1[C], g_r1[C], g_m2[C], g_r2[C], g_m3[C], g_r3[C];
__device__ float g_featp[B * 4 * C];              // head partial sums
// conv0 weights, layout [kw][o][i] (i-stride I0), fp16
__device__ _Float16 g_w0f[3 * C * I0];
// main conv weights, MFMA-native layout [kw][kseg=i>>3][o][j=i&7], fp16
__device__ _Float16 g_w1f[9 * C * C];
__device__ _Float16 g_w2f[9 * C * C];
__device__ _Float16 g_w3f[1 * C * C];

__device__ inline half8 h8zero() {
  half8 v;
#pragma unroll
  for (int j = 0; j < 8; j++) v[j] = (_Float16)0.f;
  return v;
}

__inline__ __device__ float wave_sum(float v) {
  for (int off = 32; off; off >>= 1) v += __shfl_down(v, off);
  return v;
}

// ---------------------------------------------------------------------------
// Weight prep: w [O][I][KW] fp32 -> fp16, layout [kw][i>>3][o][i&7]
// ---------------------------------------------------------------------------
template <int KW>
__global__ __launch_bounds__(256) void prep_weights_f16(
    const float* __restrict__ w, _Float16* __restrict__ wf) {
  int idx = blockIdx.x * 256 + threadIdx.x;
  if (idx >= C * C * KW) return;
  int kw = idx % KW;
  int i = (idx / KW) % C;
  int o = idx / (KW * C);
  size_t dst = (((size_t)kw * 16 + (i >> 3)) * C + o) * 8 + (i & 7);
  wf[dst] = (_Float16)w[idx];
}

// conv0 weights: w0 [O=128][I=80][3] -> [3][O][I0=96] fp16 (zero-padded i>=80)
__global__ __launch_bounds__(256) void prep_w0_f16(
    const float* __restrict__ w, _Float16* __restrict__ wf) {
  int idx = blockIdx.x * 256 + threadIdx.x;
  if (idx >= 3 * C * I0) return;
  int i = idx % I0;
  int o = (idx / I0) % C;
  int kw = idx / (I0 * C);
  float v = 0.f;
  if (i < CIN) v = w[((size_t)o * CIN + i) * 3 + kw];
  wf[((size_t)kw * C + o) * I0 + i] = (_Float16)v;
}

// ---------------------------------------------------------------------------
// Reduce partials -> mean, rstd per channel.
// ---------------------------------------------------------------------------
__device__ inline void reduce_one(const float* __restrict__ ps,
                                  const float* __restrict__ pq,
                                  float* __restrict__ om,
                                  float* __restrict__ orr, int c) {
  float s = 0.f, q = 0.f;
  for (int p = threadIdx.x; p < NPART; p += 256) {
    s += ps[c * NPART + p];
    q += pq[c * NPART + p];
  }
  s = wave_sum(s);
  q = wave_sum(q);
  __shared__ float ls[8];
  int wv = threadIdx.x >> 6, ln = threadIdx.x & 63;
  if (ln == 0) { ls[wv] = s; ls[4 + wv] = q; }
  __syncthreads();
  if (threadIdx.x == 0) {
    float S = ls[0] + ls[1] + ls[2] + ls[3];
    float Q = ls[4] + ls[5] + ls[6] + ls[7];
    const float invn = 1.f / 64000.f;
    float m = S * invn;
    float v = Q * invn - m * m;
    om[c] = m;
    orr[c] = rsqrtf(v + 1e-5f);
  }
}

__global__ __launch_bounds__(256) void reduce_stats(
    const float* __restrict__ ps, const float* __restrict__ pq,
    float* __restrict__ om, float* __restrict__ orr) {
  reduce_one(ps, pq, om, orr, blockIdx.x);
}

__global__ __launch_bounds__(256) void reduce_stats2(
    const float* __restrict__ psA, const float* __restrict__ pqA,
    float* __restrict__ omA, float* __restrict__ orA,
    const float* __restrict__ psB, const float* __restrict__ pqB,
    float* __restrict__ omB, float* __restrict__ orB) {
  if (blockIdx.y == 0)
    reduce_one(psA, pqA, omA, orA, blockIdx.x);
  else
    reduce_one(psB, pqB, omB, orB, blockIdx.x);
}

// ---------------------------------------------------------------------------
// Epilogues: store D tiles (fp32 or fp16 out) + per-channel partial stats
// into LDS ssum/ssq (LDS atomics only — globals are plain per-block stores).
// D layout (16x16x32): col(t)=lane&15, row(o)=quad*4+reg.
// ---------------------------------------------------------------------------
template <int NG, int NTG>
__device__ inline void store_and_stats_f(f32x4 (&dacc)[NG][NTG],
                                         float* __restrict__ outb,
                                         float* __restrict__ ssum,
                                         float* __restrict__ ssq, int tbase,
                                         int og0, int quad, int m15) {
#pragma unroll
  for (int g = 0; g < NG; g++) {
    float rs[4] = {0.f, 0.f, 0.f, 0.f}, rq[4] = {0.f, 0.f, 0.f, 0.f};
#pragma unroll
    for (int tg = 0; tg < NTG; tg++) {
      int t = tbase + tg * 16 + m15;
      bool valid = t < T;
      f32x4 d = dacc[g][tg];
      if (valid)
        *(f32x4*)(outb + (size_t)t * C + (og0 + g) * 16 + quad * 4) = d;
#pragma unroll
      for (int r = 0; r < 4; r++) {
        float v = valid ? d[r] : 0.f;
        rs[r] += v;
        rq[r] += v * v;
      }
    }
#pragma unroll
    for (int sh = 1; sh < 16; sh <<= 1) {
#pragma unroll
      for (int r = 0; r < 4; r++) {
        rs[r] += __shfl_xor(rs[r], sh);
        rq[r] += __shfl_xor(rq[r], sh);
      }
    }
    if (m15 == 0) {
      int o = (og0 + g) * 16 + quad * 4;
#pragma unroll
      for (int r = 0; r < 4; r++) {
        atomicAdd(&ssum[o + r], rs[r]);
        atomicAdd(&ssq[o + r], rq[r]);
      }
    }
  }
}

template <int NG, int NTG>
__device__ inline void store_and_stats_h(f32x4 (&dacc)[NG][NTG],
                                         _Float16* __restrict__ outb,
                                         float* __restrict__ ssum,
                                         float* __restrict__ ssq, int tbase,
                                         int og0, int quad, int m15) {
#pragma unroll
  for (int g = 0; g < NG; g++) {
    float rs[4] = {0.f, 0.f, 0.f, 0.f}, rq[4] = {0.f, 0.f, 0.f, 0.f};
#pragma unroll
    for (int tg = 0; tg < NTG; tg++) {
      int t = tbase + tg * 16 + m15;
      bool valid = t < T;
      f32x4 d = dacc[g][tg];
      if (valid) {
        half4 h;
#pragma unroll
        for (int r = 0; r < 4; r++) h[r] = (_Float16)d[r];
        *(half4*)(outb + (size_t)t * C + (og0 + g) * 16 + quad * 4) = h;
      }
#pragma unroll
      for (int r = 0; r < 4; r++) {
        float v = valid ? d[r] : 0.f;
        rs[r] += v;
        rq[r] += v * v;
      }
    }
#pragma unroll
    for (int sh = 1; sh < 16; sh <<= 1) {
#pragma unroll
      for (int r = 0; r < 4; r++) {
        rs[r] += __shfl_xor(rs[r], sh);
        rq[r] += __shfl_xor(rq[r], sh);
      }
    }
    if (m15 == 0) {
      int o = (og0 + g) * 16 + quad * 4;
#pragma unroll
      for (int r = 0; r < 4; r++) {
        atomicAdd(&ssum[o + r], rs[r]);
        atomicAdd(&ssq[o + r], rq[r]);
      }
    }
  }
}

// ---------------------------------------------------------------------------
// conv13f: fused combine(i-1) + conv1 (KW=9) + conv3 (KW=1).
// Staging computes k = relu(bn2(t2)+relu(bn3(t3))), va, zin inline (mode=1)
// and puts zin straight into LDS — no zi16 global round-trip. Owned rows
// write acc (non-fin) or z_next (fin); halo rows compute-only. Ping-pong
// buffers (zc->zn, accr->accw) kill dispatch-internal RAW races.
// mode=0 (first iteration): pure copy from zi16.
// Minimal-A geometry: 4 waves, og0=wv*2, NTG=4 (R10's proven shape).
// ---------------------------------------------------------------------------
__global__ __launch_bounds__(256, 4) void conv13f(
    const _Float16* __restrict__ zi, const _Float16* __restrict__ t2g,
    const _Float16* __restrict__ t3g, const float* __restrict__ m2,
    const float* __restrict__ r2, const float* __restrict__ m3,
    const float* __restrict__ r3, const float* __restrict__ zc,
    const _Float16* __restrict__ accr, float* __restrict__ zn,
    _Float16* __restrict__ accw, const _Float16* __restrict__ w9,
    const _Float16* __restrict__ w1, _Float16* __restrict__ out1,
    _Float16* __restrict__ out3, float* __restrict__ ps1,
    float* __restrict__ pq1, float* __restrict__ ps3,
    float* __restrict__ pq3, float wacc, float anext, int mode, int initf,
    int finf) {
  constexpr int PAD = 4;
  constexpr int ROWS = NT + 8;  // 72
  __shared__ __align__(16) _Float16 sh[ROWS * WPAD];
  __shared__ float ssum1[C], ssq1[C], ssum3[C], ssq3[C];
  __shared__ float sm2[C], sr2[C], sm3[C], sr3[C];

  const int tid = threadIdx.x;
  const int tile = blockIdx.x;
  const int b = blockIdx.y;
  const int t0 = tile * NT;

  if (tid < 128) {
    ssum1[tid] = 0.f; ssq1[tid] = 0.f;
    ssum3[tid] = 0.f; ssq3[tid] = 0.f;
    if (mode) {
      sm2[tid] = m2[tid]; sr2[tid] = r2[tid];
      sm3[tid] = m3[tid]; sr3[tid] = r3[tid];
    }
  }
  __syncthreads();  // BN params ready before staging uses them

  for (int e = tid; e < ROWS * 16; e += 256) {
    int r = e >> 4;
    int c8 = e & 15;
    int t = t0 - PAD + r;
    half8 v = h8zero();
    if (t >= 0 && t < T) {
      size_t off = (size_t)b * T * C + (size_t)t * C + c8 * 8;
      if (mode == 0) {
        v = *(const half8*)(zi + off);
      } else {
        half8 h2 = *(const half8*)(t2g + off);
        half8 h3 = *(const half8*)(t3g + off);
        float4 z0 = *(const float4*)(zc + off);
        float4 z1 = *(const float4*)(zc + off + 4);
        float zf[8] = {z0.x, z0.y, z0.z, z0.w, z1.x, z1.y, z1.z, z1.w};
        half8 ha = h8zero();
        if (!initf) ha = *(const half8*)(accr + off);
        int c = c8 * 8;
        float va[8], zo[8];
#pragma unroll
        for (int j = 0; j < 8; j++) {
          float f2 = (float)h2[j];
          float f3 = (float)h3[j];
          float k = fmaxf((f2 - sm2[c + j]) * sr2[c + j] +
                              fmaxf((f3 - sm3[c + j]) * sr3[c + j], 0.f),
                          0.f);
          va[j] = initf ? wacc * k : (float)ha[j] + wacc * k;
          zo[j] = zf[j] + anext * (finf ? va[j] : k);
          v[j] = (_Float16)zo[j];
        }
        bool owned = (r >= PAD) && (r < PAD + NT);
        if (owned) {
          if (finf) {
            *(float4*)(zn + off) = make_float4(zo[0], zo[1], zo[2], zo[3]);
            *(float4*)(zn + off + 4) = make_float4(zo[4], zo[5], zo[6], zo[7]);
          } else {
            half8 aw;
#pragma unroll
            for (int j = 0; j < 8; j++) aw[j] = (_Float16)va[j];
            *(half8*)(accw + off) = aw;
          }
        }
      }
    }
    *(half8*)&sh[r * WPAD + c8 * 8] = v;
  }
  __syncthreads();

  const int wv = tid >> 6;
  const int lane = tid & 63;
  const int quad = lane >> 4;
  const int m15 = lane & 15;
  const int og0 = wv * 2;  // waves own disjoint o-pairs: no A duplication

  const half8* __restrict__ A9 = (const half8*)w9;
  const half8* __restrict__ A1 = (const half8*)w1;

  // --- conv3 (KW=1): 4 rounds, retire accumulator early ---
  {
    f32x4 d3[2][4];
#pragma unroll
    for (int g = 0; g < 2; g++)
#pragma unroll
      for (int tg = 0; tg < 4; tg++) d3[g][tg] = f32x4{0.f, 0.f, 0.f, 0.f};
#pragma unroll
    for (int ic = 0; ic < 4; ic++) {
      const int kof = ic * 32 + quad * 8;
      half8 af[2];
#pragma unroll
      for (int g = 0; g < 2; g++)
        af[g] = A1[(ic * 4 + quad) * C + (og0 + g) * 16 + m15];
      half8 bf[4];
#pragma unroll
      for (int tg = 0; tg < 4; tg++)
        bf[tg] = *(const half8*)(sh + (tg * 16 + m15 + PAD) * WPAD + kof);
#pragma unroll
      for (int g = 0; g < 2; g++)
#pragma unroll
        for (int tg = 0; tg < 4; tg++)
          d3[g][tg] = __builtin_amdgcn_mfma_f32_16x16x32_f16(
              af[g], bf[tg], d3[g][tg], 0, 0, 0);
    }
    _Float16* __restrict__ o3b = out3 + (size_t)b * T * C;
    store_and_stats_h<2, 4>(d3, o3b, ssum3, ssq3, t0, og0, quad, m15);
  }

  // --- conv1 (KW=9): 36 rounds ---
  f32x4 d1[2][4];
#pragma unroll
  for (int g = 0; g < 2; g++)
#pragma unroll
    for (int tg = 0; tg < 4; tg++) d1[g][tg] = f32x4{0.f, 0.f, 0.f, 0.f};

  for (int kw = 0; kw < 9; kw++) {
#pragma unroll
    for (int ic = 0; ic < 4; ic++) {
      const int kof = ic * 32 + quad * 8;
      half8 af[2];
#pragma unroll
      for (int g = 0; g < 2; g++)
        af[g] = A9[(kw * 16 + ic * 4 + quad) * C + (og0 + g) * 16 + m15];
      half8 bf[4];
#pragma unroll
      for (int tg = 0; tg < 4; tg++)
        bf[tg] = *(const half8*)(sh + (tg * 16 + m15 + kw) * WPAD + kof);
#pragma unroll
      for (int g = 0; g < 2; g++)
#pragma unroll
        for (int tg = 0; tg < 4; tg++)
          d1[g][tg] = __builtin_amdgcn_mfma_f32_16x16x32_f16(
              af[g], bf[tg], d1[g][tg], 0, 0, 0);
    }
  }

  _Float16* __restrict__ o1b = out1 + (size_t)b * T * C;
  store_and_stats_h<2, 4>(d1, o1b, ssum1, ssq1, t0, og0, quad, m15);
  __syncthreads();
  int p = b * 8 + tile;
  if (tid < 128) {
    ps1[tid * NPART + p] = ssum1[tid];
    pq1[tid * NPART + p] = ssq1[tid];
    ps3[tid * NPART + p] = ssum3[tid];
    pq3[tid * NPART + p] = ssq3[tid];
  }
}

// ---------------------------------------------------------------------------
// conv2 (KW=9, PAD=4): BN+relu on staging from precomputed mean/rstd;
// minimal-A geometry; per-block partial stats store.
// ---------------------------------------------------------------------------
__global__ __launch_bounds__(256, 4) void conv2_bn(
    const _Float16* __restrict__ in, const _Float16* __restrict__ wf,
    const float* __restrict__ bnm, const float* __restrict__ bnr,
    _Float16* __restrict__ out, float* __restrict__ ps,
    float* __restrict__ pq) {
  constexpr int KW = 9, PAD = 4;
  constexpr int ROWS = NT + KW - 1;  // 72
  __shared__ __align__(16) _Float16 sh[ROWS * WPAD];
  __shared__ float ssum[C], ssq[C];
  __shared__ float sbm[C], sbr[C];

  const int tid = threadIdx.x;
  const int tile = blockIdx.x;
  const int b = blockIdx.y;
  const int t0 = tile * NT;

  if (tid < 128) {
    sbm[tid] = bnm[tid];
    sbr[tid] = bnr[tid];
    ssum[tid] = 0.f;
    ssq[tid] = 0.f;
  }
  __syncthreads();  // BN params ready before staging uses them

  const _Float16* __restrict__ inb = in + (size_t)b * T * C;
  for (int e = tid; e < ROWS * 16; e += 256) {
    int r = e >> 4;
    int c8 = e & 15;
    int t = t0 - PAD + r;
    half8 v = h8zero();
    if (t >= 0 && t < T) {
      half8 u = *(const half8*)(inb + (size_t)t * C + c8 * 8);
      int c = c8 * 8;
#pragma unroll
      for (int j = 0; j < 8; j++) {
        float f = (float)u[j];
        f = fmaxf((f - sbm[c + j]) * sbr[c + j], 0.f);
        v[j] = (_Float16)f;
      }
    }
    *(half8*)&sh[r * WPAD + c8 * 8] = v;
  }
  __syncthreads();

  const int wv = tid >> 6;
  const int lane = tid & 63;
  const int quad = lane >> 4;
  const int m15 = lane & 15;
  const int og0 = wv * 2;

  const half8* __restrict__ Af = (const half8*)wf;

  f32x4 dacc[2][4];
#pragma unroll
  for (int g = 0; g < 2; g++)
#pragma unroll
    for (int tg = 0; tg < 4; tg++) dacc[g][tg] = f32x4{0.f, 0.f, 0.f, 0.f};

  for (int kw = 0; kw < 9; kw++) {
#pragma unroll
    for (int ic = 0; ic < 4; ic++) {
      const int kof = ic * 32 + quad * 8;
      half8 af[2];
#pragma unroll
      for (int g = 0; g < 2; g++)
        af[g] = Af[(kw * 16 + ic * 4 + quad) * C + (og0 + g) * 16 + m15];
      half8 bf[4];
#pragma unroll
      for (int tg = 0; tg < 4; tg++)
        bf[tg] = *(const half8*)(sh + (tg * 16 + m15 + kw) * WPAD + kof);
#pragma unroll
      for (int g = 0; g < 2; g++)
#pragma unroll
        for (int tg = 0; tg < 4; tg++)
          dacc[g][tg] = __builtin_amdgcn_mfma_f32_16x16x32_f16(
              af[g], bf[tg], dacc[g][tg], 0, 0, 0);
    }
  }

  _Float16* __restrict__ outb = out + (size_t)b * T * C;
  store_and_stats_h<2, 4>(dacc, outb, ssum, ssq, t0, og0, quad, m15);
  __syncthreads();
  int p = b * 8 + tile;
  if (tid < 128) {
    ps[tid * NPART + p] = ssum[tid];
    pq[tid * NPART + p] = ssq[tid];
  }
}

// ---------------------------------------------------------------------------
// conv0: single fp16 16x16x32 MFMA. in x[B][80][T] (t fastest), K=96(pad) x 3.
// Output z fp32 (state); per-block partial stats.
// ---------------------------------------------------------------------------
__global__ __launch_bounds__(256) void conv0_mfma(
    const float* __restrict__ in, const _Float16* __restrict__ wf,
    float* __restrict__ out, float* __restrict__ ps, float* __restrict__ pq) {
  constexpr int KW = 3, PAD = 1;
  constexpr int ROWS = NT + KW - 1;  // 66
  __shared__ __align__(16) _Float16 sh[ROWS * IPAD0];
  __shared__ float ssum[C], ssq[C];

  const int tid = threadIdx.x;
  const int tile = blockIdx.x;
  const int b = blockIdx.y;
  const int t0 = tile * NT;

  if (tid < 128) { ssum[tid] = 0.f; ssq[tid] = 0.f; }
  __syncthreads();

  const float* __restrict__ inb = in + (size_t)b * CIN * T;
  for (int e = tid; e < I0 * ROWS; e += 256) {
    int i = e / ROWS;
    int r = e % ROWS;
    int t = t0 - PAD + r;
    float v = 0.f;
    if (i < CIN && t >= 0 && t < T) v = inb[(size_t)i * T + t];
    sh[r * IPAD0 + i] = (_Float16)v;
  }
  __syncthreads();

  const int wv = tid >> 6;
  const int lane = tid & 63;
  const int quad = lane >> 4;
  const int m15 = lane & 15;
  const int og0 = wv * 2;

  f32x4 dacc[2][4];
#pragma unroll
  for (int g = 0; g < 2; g++)
#pragma unroll
    for (int tg = 0; tg < 4; tg++) dacc[g][tg] = f32x4{0.f, 0.f, 0.f, 0.f};

  for (int kw = 0; kw < KW; kw++) {
    const _Float16* __restrict__ wk = wf + (size_t)kw * C * I0;
#pragma unroll
    for (int ic = 0; ic < 3; ic++) {
      const int kof = ic * 32 + quad * 8;
      half8 af[2];
#pragma unroll
      for (int g = 0; g < 2; g++) {
        size_t off = (size_t)((og0 + g) * 16 + m15) * I0 + kof;
        af[g] = *(const half8*)(wk + off);
      }
      half8 bf[4];
#pragma unroll
      for (int tg = 0; tg < 4; tg++) {
        int off = (tg * 16 + m15 + kw) * IPAD0 + kof;
        bf[tg] = *(const half8*)(sh + off);
      }
#pragma unroll
      for (int g = 0; g < 2; g++)
#pragma unroll
        for (int tg = 0; tg < 4; tg++)
          dacc[g][tg] = __builtin_amdgcn_mfma_f32_16x16x32_f16(
              af[g], bf[tg], dacc[g][tg], 0, 0, 0);
    }
  }

  float* __restrict__ outb = out + (size_t)b * T * C;
  store_and_stats_f<2, 4>(dacc, outb, ssum, ssq, t0, og0, quad, m15);
  __syncthreads();
  int p = b * 8 + tile;
  if (tid < 128) {
    ps[tid * NPART + p] = ssum[tid];
    pq[tid * NPART + p] = ssq[tid];
  }
}

// ---------------------------------------------------------------------------
// z = relu((z - m[c]) * r[c]) in place (fp32) + fp16 snapshot for conv13f(0).
// ---------------------------------------------------------------------------
__global__ __launch_bounds__(256) void apply_bn_relu(
    float* __restrict__ x, const float* __restrict__ m,
    const float* __restrict__ r, _Float16* __restrict__ zh) {
  __shared__ float sm[C], sr[C];
  if (threadIdx.x < 128) {
    sm[threadIdx.x] = m[threadIdx.x];
    sr[threadIdx.x] = r[threadIdx.x];
  }
  __syncthreads();
  const size_t total4 = NBCT / 4;
  size_t stride = (size_t)gridDim.x * 256;
  for (size_t i4 = (size_t)blockIdx.x * 256 + threadIdx.x; i4 < total4;
       i4 += stride) {
    int c = (int)((i4 & 31) * 4);
    float4 v = ((float4*)x)[i4];
    v.x = fmaxf((v.x - sm[c]) * sr[c], 0.f);
    v.y = fmaxf((v.y - sm[c + 1]) * sr[c + 1], 0.f);
    v.z = fmaxf((v.z - sm[c + 2]) * sr[c + 2], 0.f);
    v.w = fmaxf((v.w - sm[c + 3]) * sr[c + 3], 0.f);
    ((float4*)x)[i4] = v;
    half4 h;
    h[0] = (_Float16)v.x;
    h[1] = (_Float16)v.y;
    h[2] = (_Float16)v.z;
    h[3] = (_Float16)v.w;
    *(half4*)(zh + i4 * 4) = h;
  }
}

// ---------------------------------------------------------------------------
// Final combine (one dispatch, fin): z_new = z + anext*(acc + wacc*k).
// In-place on z (standalone dispatch -> no halo race).
// ---------------------------------------------------------------------------
__global__ __launch_bounds__(256) void combine_fin(
    const _Float16* __restrict__ t2, const _Float16* __restrict__ t3,
    const float* __restrict__ m2, const float* __restrict__ r2,
    const float* __restrict__ m3, const float* __restrict__ r3,
    float* __restrict__ z, const _Float16* __restrict__ acc, float wacc,
    float anext) {
  __shared__ float sm2[C], sr2[C], sm3[C], sr3[C];
  if (threadIdx.x < 128) {
    sm2[threadIdx.x] = m2[threadIdx.x];
    sr2[threadIdx.x] = r2[threadIdx.x];
    sm3[threadIdx.x] = m3[threadIdx.x];
    sr3[threadIdx.x] = r3[threadIdx.x];
  }
  __syncthreads();
  const size_t total4 = NBCT / 4;
  size_t stride = (size_t)gridDim.x * 256;
  for (size_t i4 = (size_t)blockIdx.x * 256 + threadIdx.x; i4 < total4;
       i4 += stride) {
    int c = (int)((i4 & 31) * 4);
    size_t off = i4 * 4;
    half4 h2 = *(const half4*)(t2 + off);
    half4 h3 = *(const half4*)(t3 + off);
    half4 ha = *(const half4*)(acc + off);
    float4 vz = *(const float4*)(z + off);
    float vzf[4] = {vz.x, vz.y, vz.z, vz.w};
    float vo[4];
#pragma unroll
    for (int j = 0; j < 4; j++) {
      float f2 = (float)h2[j];
      float f3 = (float)h3[j];
      float k = fmaxf((f2 - sm2[c + j]) * sr2[c + j] +
                          fmaxf((f3 - sm3[c + j]) * sr3[c + j], 0.f),
                      0.f);
      float va = (float)ha[j] + wacc * k;
      vo[j] = vzf[j] + anext * va;
    }
    *(float4*)(z + off) = make_float4(vo[0], vo[1], vo[2], vo[3]);
  }
}

// ---------------------------------------------------------------------------
// head, phase 1: partial t-sums. grid (B, 4), each block sums 125 t's.
// ---------------------------------------------------------------------------
__global__ __launch_bounds__(256) void feat_part(
    const float* __restrict__ z, float* __restrict__ fp) {
  const int b = blockIdx.x;
  const int s = blockIdx.y;
  const int c = threadIdx.x & 127;
  const int h = threadIdx.x >> 7;
  const float* zb = z + (size_t)b * T * C;
  float sum = 0.f;
  for (int t = s * 125 + h; t < (s + 1) * 125; t += 2)
    sum += zb[(size_t)t * C + c];
  __shared__ float sf[2][C];
  sf[h][c] = sum;
  __syncthreads();
  if (threadIdx.x < 128)
    fp[((size_t)b * 4 + s) * C + threadIdx.x] =
        sf[0][threadIdx.x] + sf[1][threadIdx.x];
}

// head, phase 2: feat = sum(partials)/500; out = feat @ ow^T + ob.
__global__ __launch_bounds__(256) void head2(
    const float* __restrict__ fp, const float* __restrict__ ow,
    const float* __restrict__ ob, float* __restrict__ out) {
  const int b = blockIdx.x;
  __shared__ float feat[C];
  if (threadIdx.x < 128) {
    float s = 0.f;
#pragma unroll
    for (int p = 0; p < 4; p++) s += fp[((size_t)b * 4 + p) * C + threadIdx.x];
    feat[threadIdx.x] = s * (1.f / 500.f);
  }
  __syncthreads();
  if (threadIdx.x < NL) {
    int l = threadIdx.x;
    float o = ob[l];
    for (int j = 0; j < C; j++) o = fmaf(feat[j], ow[l * C + j], o);
    out[b * NL + l] = o;
  }
}

// ---------------------------------------------------------------------------
extern "C" void kernel_launch(void* const* d_in, const int* in_sizes, int n_in,
                              void* d_out, int out_size, void* d_ws,
                              size_t ws_size, hipStream_t stream) {
  const float* x  = (const float*)d_in[0];
  const float* w0 = (const float*)d_in[1];
  const float* w1 = (const float*)d_in[2];
  const float* w2 = (const float*)d_in[3];
  const float* w3 = (const float*)d_in[4];
  const float* ow = (const float*)d_in[5];
  const float* ob = (const float*)d_in[6];
  float* out = (float*)d_out;

  static float *zA, *zB, *featp;
  static float *ps1, *pq1, *ps2, *pq2, *ps3, *pq3;
  static float *m1, *r1, *m2, *r2, *m3, *r3;
  static _Float16 *accA, *accB, *zi16, *t1, *t2, *t3;
  static _Float16 *w0f, *w1f, *w2f, *w3f;
  static bool inited = false;
  if (!inited) {
    void* p;
#define GET(sym, var) hipGetSymbolAddress(&p, HIP_SYMBOL(sym)); var = (decltype(var))p;
    GET(g_zA, zA) GET(g_zB, zB) GET(g_accA, accA) GET(g_accB, accB)
    GET(g_zi16, zi16)
    GET(g_t1, t1) GET(g_t2, t2) GET(g_t3, t3)
    GET(g_ps1, ps1) GET(g_pq1, pq1) GET(g_ps2, ps2) GET(g_pq2, pq2)
    GET(g_ps3, ps3) GET(g_pq3, pq3)
    GET(g_m1, m1) GET(g_r1, r1) GET(g_m2, m2) GET(g_r2, r2)
    GET(g_m3, m3) GET(g_r3, r3) GET(g_featp, featp)
    GET(g_w0f, w0f) GET(g_w1f, w1f) GET(g_w2f, w2f) GET(g_w3f, w3f)
#undef GET
    inited = true;
  }

  // Weight prep (cheap, every launch)
  prep_w0_f16<<<(3 * C * I0 + 255) / 256, 256, 0, stream>>>(w0, w0f);
  prep_weights_f16<9><<<(C * C * 9 + 255) / 256, 256, 0, stream>>>(w1, w1f);
  prep_weights_f16<9><<<(C * C * 9 + 255) / 256, 256, 0, stream>>>(w2, w2f);
  prep_weights_f16<1><<<(C * C * 1 + 255) / 256, 256, 0, stream>>>(w3, w3f);

  const dim3 convGrid(8, B);   // NT=64 tiles -> 1024 blocks of 256 thr
  const int ewGrid = 1024;
  const float dt = 0.25f;

  // conv0 -> reduce -> bn+relu (into zA fp32 + zi16 fp16).
  conv0_mfma<<<dim3(8, B), 256, 0, stream>>>(x, w0f, zA, ps1, pq1);
  reduce_stats<<<C, 256, 0, stream>>>(ps1, pq1, m1, r1);
  apply_bn_relu<<<ewGrid, 256, 0, stream>>>(zA, m1, r1, zi16);

  const float waccs[4] = {1.f, 2.f, 2.f, 1.f};
  const float anexts[4] = {0.5f * dt, 0.5f * dt, dt, dt / 6.f};

  float* zcur = zA;
  float* znext = zB;
  _Float16* accbuf[2] = {accA, accB};
  int flip = 0;

  for (int i = 0; i < 16; i++) {
    int sp = (i + 3) % 4;  // previous iteration's s (valid for i>=1)
    int mode = (i == 0) ? 0 : 1;
    int initf = (sp == 0) ? 1 : 0;
    int finf = (sp == 3) ? 1 : 0;
    conv13f<<<convGrid, 256, 0, stream>>>(
        zi16, t2, t3, m2, r2, m3, r3, zcur, accbuf[flip], znext,
        accbuf[flip ^ 1], w1f, w3f, t1, t3, ps1, pq1, ps3, pq3,
        mode ? waccs[sp] : 0.f, mode ? anexts[sp] : 0.f, mode, initf, finf);
    if (i >= 1) {
      if (!finf) {
        flip ^= 1;                       // acc written into flip^1
      } else {
        float* tmp = zcur; zcur = znext; znext = tmp;  // fin wrote z
      }
    }
    reduce_stats2<<<dim3(C, 2), 256, 0, stream>>>(
        ps1, pq1, m1, r1, ps3, pq3, m3, r3);
    conv2_bn<<<convGrid, 256, 0, stream>>>(
        t1, w2f, m1, r1, t2, ps2, pq2);
    reduce_stats<<<C, 256, 0, stream>>>(ps2, pq2, m2, r2);
  }

  // Final combine (fin of step 3, s=3): in-place on zcur.
  combine_fin<<<ewGrid, 256, 0, stream>>>(
      t2, t3, m2, r2, m3, r3, zcur, accbuf[flip], 1.f, dt / 6.f);

  feat_part<<<dim3(B, 4), 256, 0, stream>>>(zcur, featp);
  head2<<<B, 256, 0, stream>>>(featp, ow, ob, out);
}